// Round 1
// baseline (313.141 us; speedup 1.0000x reference)
//
#include <hip/hip_runtime.h>
#include <hip/hip_bf16.h>
#include <cstddef>

// ---------------------------------------------------------------------------
// 2-layer GCN: h1 = x@W1; hmid = relu(Agg(h1) + b1); h2 = hmid@W2;
// out = Agg(h2) + b2.  Agg = sym-normalized scatter-add with self-loops.
// Strategy: build CSR-by-dst once (deg count -> single-block scan -> fill),
// pull-mode aggregation (one wave per node, coalesced gathers, no atomics
// in the hot loop), register-blocked fp32 GEMMs with LDS-staged tiles.
// ---------------------------------------------------------------------------

#define N_NODES_EXPECT 50000

__global__ __launch_bounds__(256) void zero_int_kernel(int* __restrict__ p, int n) {
    int i = blockIdx.x * blockDim.x + threadIdx.x;
    if (i < n) p[i] = 0;
}

__global__ __launch_bounds__(256) void count_kernel(const int* __restrict__ dst, int E,
                                                    int* __restrict__ deg) {
    int i = blockIdx.x * blockDim.x + threadIdx.x;
    if (i < E) atomicAdd(&deg[dst[i]], 1);
}

__global__ __launch_bounds__(256) void dinv_kernel(const int* __restrict__ deg,
                                                   float* __restrict__ dinv, int n) {
    int i = blockIdx.x * blockDim.x + threadIdx.x;
    if (i < n) {
        // +1 self loop; deg >= 1 always
        dinv[i] = rsqrtf((float)(deg[i] + 1));
    }
}

// Single-block exclusive scan over deg -> offs (and cur copy). n ~ 50000.
__global__ __launch_bounds__(1024) void scan_kernel(const int* __restrict__ deg,
                                                    int* __restrict__ offs,
                                                    int* __restrict__ cur, int n) {
    __shared__ int wsum[16];
    __shared__ int s_carry;
    int tid = threadIdx.x;
    int lane = tid & 63;
    int wid = tid >> 6;
    if (tid == 0) s_carry = 0;
    __syncthreads();
    for (int base = 0; base < n; base += 1024) {
        int i = base + tid;
        int v = (i < n) ? deg[i] : 0;
        // inclusive wave scan
        int x = v;
        #pragma unroll
        for (int off = 1; off < 64; off <<= 1) {
            int y = __shfl_up(x, off, 64);
            if (lane >= off) x += y;
        }
        if (lane == 63) wsum[wid] = x;
        __syncthreads();
        int carry = s_carry;
        if (wid == 0) {
            int ws = (lane < 16) ? wsum[lane] : 0;
            #pragma unroll
            for (int off = 1; off < 16; off <<= 1) {
                int y = __shfl_up(ws, off, 64);
                if (lane >= off) ws += y;
            }
            if (lane < 16) wsum[lane] = ws;  // inclusive wave-sums
        }
        __syncthreads();
        int wprefix = (wid == 0) ? 0 : wsum[wid - 1];
        int incl = carry + wprefix + x;
        int excl = incl - v;
        if (i < n) { offs[i] = excl; cur[i] = excl; }
        __syncthreads();  // everyone done reading wsum/s_carry
        if (tid == 1023) s_carry = incl;
        __syncthreads();
    }
    if (tid == 0) offs[n] = s_carry;
}

__global__ __launch_bounds__(256) void fill_kernel(const int* __restrict__ src,
                                                   const int* __restrict__ dst, int E,
                                                   int* __restrict__ cur,
                                                   const float* __restrict__ dinv,
                                                   int* __restrict__ csr_src,
                                                   float* __restrict__ csr_norm) {
    int i = blockIdx.x * blockDim.x + threadIdx.x;
    if (i < E) {
        int s = src[i];
        int d = dst[i];
        int p = atomicAdd(&cur[d], 1);
        csr_src[p] = s;
        csr_norm[p] = dinv[s] * dinv[d];
    }
}

// ---------------------------------------------------------------------------
// fp32 GEMM: C[M, TN] = A[M,128] @ B[128,TN].  TN in {128, 64}.
// 256 threads; per-thread 4 rows x 8 cols (two float4 col slabs at c and
// c + TN/2). A staged transposed in LDS (k-major), B staged k-major.
// K chunked by 64 to stay under 64 KB LDS.
// ---------------------------------------------------------------------------
template <int TN>
__global__ __launch_bounds__(256) void gemm_kernel(const float* __restrict__ A,
                                                   const float* __restrict__ B,
                                                   float* __restrict__ C, int M) {
    constexpr int K = 128;
    constexpr int KC = 64;
    constexpr int CG = TN / 8;        // col groups
    constexpr int TM = 1024 / CG;     // rows per block (64 or 128)
    constexpr int PAD = 4;

    __shared__ float At[KC][TM + PAD];  // [k][row]
    __shared__ float Bs[KC][TN + PAD];  // [k][col]

    int tid = threadIdx.x;
    int tx = tid % CG;
    int ty = tid / CG;
    int r  = ty * 4;            // local row base
    int c0 = tx * 4;            // first col slab
    int c1 = TN / 2 + tx * 4;   // second col slab
    int row0 = blockIdx.x * TM;

    float acc[4][8];
    #pragma unroll
    for (int i = 0; i < 4; i++)
        #pragma unroll
        for (int j = 0; j < 8; j++) acc[i][j] = 0.f;

    for (int kc = 0; kc < K; kc += KC) {
        __syncthreads();
        // stage A (TM x KC) transposed -> At[k][row]
        constexpr int AITEMS = TM * (KC / 4) / 256;
        #pragma unroll
        for (int it = 0; it < AITEMS; it++) {
            int idx = tid + it * 256;
            int row = idx / (KC / 4);
            int kq  = idx % (KC / 4);
            float4 av = make_float4(0.f, 0.f, 0.f, 0.f);
            int grow = row0 + row;
            if (grow < M)
                av = *(const float4*)(A + (size_t)grow * K + kc + kq * 4);
            At[kq * 4 + 0][row] = av.x;
            At[kq * 4 + 1][row] = av.y;
            At[kq * 4 + 2][row] = av.z;
            At[kq * 4 + 3][row] = av.w;
        }
        // stage B (KC x TN) -> Bs[k][col]
        constexpr int BITEMS = KC * (TN / 4) / 256;
        #pragma unroll
        for (int it = 0; it < BITEMS; it++) {
            int idx = tid + it * 256;
            int kk = idx / (TN / 4);
            int c4 = idx % (TN / 4);
            float4 bv = *(const float4*)(B + (size_t)(kc + kk) * TN + c4 * 4);
            *(float4*)&Bs[kk][c4 * 4] = bv;
        }
        __syncthreads();

        #pragma unroll 8
        for (int kk = 0; kk < KC; kk++) {
            float4 a  = *(const float4*)&At[kk][r];
            float4 bA = *(const float4*)&Bs[kk][c0];
            float4 bB = *(const float4*)&Bs[kk][c1];
            float av[4]; av[0] = a.x; av[1] = a.y; av[2] = a.z; av[3] = a.w;
            float bv[8];
            bv[0] = bA.x; bv[1] = bA.y; bv[2] = bA.z; bv[3] = bA.w;
            bv[4] = bB.x; bv[5] = bB.y; bv[6] = bB.z; bv[7] = bB.w;
            #pragma unroll
            for (int i = 0; i < 4; i++)
                #pragma unroll
                for (int j = 0; j < 8; j++)
                    acc[i][j] += av[i] * bv[j];
        }
    }

    #pragma unroll
    for (int i = 0; i < 4; i++) {
        int grow = row0 + r + i;
        if (grow < M) {
            float4 v0 = make_float4(acc[i][0], acc[i][1], acc[i][2], acc[i][3]);
            float4 v1 = make_float4(acc[i][4], acc[i][5], acc[i][6], acc[i][7]);
            *(float4*)(C + (size_t)grow * TN + c0) = v0;
            *(float4*)(C + (size_t)grow * TN + c1) = v1;
        }
    }
}

// ---------------------------------------------------------------------------
// Pull-mode aggregation: out[n] = sum_{e: dst=n} h[src_e]*norm_e
//                                + h[n]*dinv[n]^2 + bias  (opt ReLU)
// One wave (64 threads) per node; each thread owns D/64 contiguous floats.
// ---------------------------------------------------------------------------
template <int D, bool RELU>
__global__ __launch_bounds__(64) void agg_kernel(const float* __restrict__ h,
                                                 const int* __restrict__ offs,
                                                 const int* __restrict__ csr_src,
                                                 const float* __restrict__ csr_norm,
                                                 const float* __restrict__ dinv,
                                                 const float* __restrict__ bias,
                                                 float* __restrict__ out, int n) {
    constexpr int V = D / 64;
    int node = blockIdx.x;
    int t = threadIdx.x;

    float di = dinv[node];
    float sw = di * di;
    const float* hp = h + (size_t)node * D + t * V;
    float acc[V];
    #pragma unroll
    for (int v = 0; v < V; v++) acc[v] = hp[v] * sw;

    int e0 = offs[node];
    int e1 = offs[node + 1];
    for (int e = e0; e < e1; e++) {
        int s = csr_src[e];
        float w = csr_norm[e];
        const float* hs = h + (size_t)s * D + t * V;
        #pragma unroll
        for (int v = 0; v < V; v++) acc[v] += hs[v] * w;
    }

    float* op = out + (size_t)node * D + t * V;
    #pragma unroll
    for (int v = 0; v < V; v++) {
        float rres = acc[v] + bias[t * V + v];
        if (RELU) rres = fmaxf(rres, 0.f);
        op[v] = rres;
    }
}

extern "C" void kernel_launch(void* const* d_in, const int* in_sizes, int n_in,
                              void* d_out, int out_size, void* d_ws, size_t ws_size,
                              hipStream_t stream) {
    const float* x  = (const float*)d_in[0];
    const int*   ei = (const int*)d_in[1];
    const float* W1 = (const float*)d_in[2];
    const float* b1 = (const float*)d_in[3];
    const float* W2 = (const float*)d_in[4];
    const float* b2 = (const float*)d_in[5];

    const int N = in_sizes[0] / 128;   // 50000
    const int E = in_sizes[1] / 2;     // 500000
    const int* src = ei;
    const int* dst = ei + E;

    char* p = (char*)d_ws;
    auto alloc = [&](size_t bytes) {
        char* r = p;
        p += (bytes + 255) & ~(size_t)255;
        return r;
    };
    int*   degi     = (int*)  alloc((size_t)N * 4);
    float* dinv     = (float*)alloc((size_t)N * 4);
    int*   offs     = (int*)  alloc((size_t)(N + 1) * 4);
    int*   cur      = (int*)  alloc((size_t)N * 4);
    int*   csr_src  = (int*)  alloc((size_t)E * 4);
    float* csr_norm = (float*)alloc((size_t)E * 4);
    float* h1       = (float*)alloc((size_t)N * 128 * 4);
    float* hmid     = (float*)alloc((size_t)N * 128 * 4);
    float* h2       = h1;  // reuse: h1 dead after agg layer 1
    float* out      = (float*)d_out;

    // --- build degree / dinv / CSR (shared by both layers) ---
    zero_int_kernel<<<(N + 255) / 256, 256, 0, stream>>>(degi, N);
    count_kernel<<<(E + 255) / 256, 256, 0, stream>>>(dst, E, degi);
    dinv_kernel<<<(N + 255) / 256, 256, 0, stream>>>(degi, dinv, N);
    scan_kernel<<<1, 1024, 0, stream>>>(degi, offs, cur, N);
    fill_kernel<<<(E + 255) / 256, 256, 0, stream>>>(src, dst, E, cur, dinv,
                                                     csr_src, csr_norm);

    // --- layer 1: h1 = x @ W1; hmid = relu(Agg(h1) + b1) ---
    gemm_kernel<128><<<(N + 63) / 64, 256, 0, stream>>>(x, W1, h1, N);
    agg_kernel<128, true><<<N, 64, 0, stream>>>(h1, offs, csr_src, csr_norm,
                                                dinv, b1, hmid, N);

    // --- layer 2: h2 = hmid @ W2; out = Agg(h2) + b2 ---
    gemm_kernel<64><<<(N + 127) / 128, 256, 0, stream>>>(hmid, W2, h2, N);
    agg_kernel<64, false><<<N, 64, 0, stream>>>(h2, offs, csr_src, csr_norm,
                                                dinv, b2, out, N);
}

// Round 2
// 271.309 us; speedup vs baseline: 1.1542x; 1.1542x over previous
//
#include <hip/hip_runtime.h>
#include <hip/hip_bf16.h>
#include <cstddef>

// ---------------------------------------------------------------------------
// 2-layer GCN: h1 = x@W1; hmid = relu(Agg(h1) + b1); h2 = hmid@W2;
// out = Agg(h2) + b2.  Agg = sym-normalized scatter-add with self-loops.
// R1: replaced single-block scan (52 us, 0.16% occupancy) with 3-phase
// multi-block scan (+fused dinv), zeroing via hipMemsetAsync.
// ---------------------------------------------------------------------------

__global__ __launch_bounds__(256) void count_kernel(const int* __restrict__ dst, int E,
                                                    int* __restrict__ deg) {
    int i = blockIdx.x * blockDim.x + threadIdx.x;
    if (i < E) atomicAdd(&deg[dst[i]], 1);
}

// ---- 3-phase exclusive scan over deg[0..n) ; chunk = 1024 elems/block ----
// Phase A: per-block sum -> bsums[b]
__global__ __launch_bounds__(256) void scanA_kernel(const int* __restrict__ deg, int n,
                                                    int* __restrict__ bsums) {
    int tid = threadIdx.x;
    int lane = tid & 63;
    int wid = tid >> 6;
    int i = blockIdx.x * 1024 + tid * 4;
    int v0 = (i + 0 < n) ? deg[i + 0] : 0;
    int v1 = (i + 1 < n) ? deg[i + 1] : 0;
    int v2 = (i + 2 < n) ? deg[i + 2] : 0;
    int v3 = (i + 3 < n) ? deg[i + 3] : 0;
    int s = v0 + v1 + v2 + v3;
    #pragma unroll
    for (int off = 32; off > 0; off >>= 1) s += __shfl_down(s, off, 64);
    __shared__ int ws[4];
    if (lane == 0) ws[wid] = s;
    __syncthreads();
    if (tid == 0) bsums[blockIdx.x] = ws[0] + ws[1] + ws[2] + ws[3];
}

// Phase B: one wave scans bsums (nb <= 64) in place (exclusive), total -> *totp
__global__ __launch_bounds__(64) void scanB_kernel(int* __restrict__ bsums, int nb,
                                                   int* __restrict__ totp) {
    int lane = threadIdx.x;
    int v = (lane < nb) ? bsums[lane] : 0;
    int x = v;
    #pragma unroll
    for (int off = 1; off < 64; off <<= 1) {
        int y = __shfl_up(x, off, 64);
        if (lane >= off) x += y;
    }
    if (lane < nb) bsums[lane] = x - v;   // exclusive
    if (lane == 63) *totp = x;            // total (zeros padded above nb)
}

// Phase C: block-local exclusive scan + carry -> offs, cur; fused dinv.
__global__ __launch_bounds__(256) void scanC_kernel(const int* __restrict__ deg, int n,
                                                    const int* __restrict__ bsums,
                                                    int* __restrict__ offs,
                                                    int* __restrict__ cur,
                                                    float* __restrict__ dinv) {
    int tid = threadIdx.x;
    int lane = tid & 63;
    int wid = tid >> 6;
    int carry = bsums[blockIdx.x];
    int i = blockIdx.x * 1024 + tid * 4;
    int v0 = (i + 0 < n) ? deg[i + 0] : 0;
    int v1 = (i + 1 < n) ? deg[i + 1] : 0;
    int v2 = (i + 2 < n) ? deg[i + 2] : 0;
    int v3 = (i + 3 < n) ? deg[i + 3] : 0;
    int t = v0 + v1 + v2 + v3;
    int x = t;
    #pragma unroll
    for (int off = 1; off < 64; off <<= 1) {
        int y = __shfl_up(x, off, 64);
        if (lane >= off) x += y;
    }
    __shared__ int ws[4];
    if (lane == 63) ws[wid] = x;
    __syncthreads();
    int wprefix = 0;
    #pragma unroll
    for (int w = 0; w < 4; w++) wprefix += (w < wid) ? ws[w] : 0;
    int e0 = carry + wprefix + x - t;  // exclusive at element i
    int e1 = e0 + v0, e2 = e1 + v1, e3 = e2 + v2;
    if (i + 0 < n) { offs[i + 0] = e0; cur[i + 0] = e0; dinv[i + 0] = rsqrtf((float)(v0 + 1)); }
    if (i + 1 < n) { offs[i + 1] = e1; cur[i + 1] = e1; dinv[i + 1] = rsqrtf((float)(v1 + 1)); }
    if (i + 2 < n) { offs[i + 2] = e2; cur[i + 2] = e2; dinv[i + 2] = rsqrtf((float)(v2 + 1)); }
    if (i + 3 < n) { offs[i + 3] = e3; cur[i + 3] = e3; dinv[i + 3] = rsqrtf((float)(v3 + 1)); }
}

__global__ __launch_bounds__(256) void fill_kernel(const int* __restrict__ src,
                                                   const int* __restrict__ dst, int E,
                                                   int* __restrict__ cur,
                                                   const float* __restrict__ dinv,
                                                   int* __restrict__ csr_src,
                                                   float* __restrict__ csr_norm) {
    int i = blockIdx.x * blockDim.x + threadIdx.x;
    if (i < E) {
        int s = src[i];
        int d = dst[i];
        int p = atomicAdd(&cur[d], 1);
        csr_src[p] = s;
        csr_norm[p] = dinv[s] * dinv[d];
    }
}

// ---------------------------------------------------------------------------
// fp32 GEMM: C[M, TN] = A[M,128] @ B[128,TN].  TN in {128, 64}.
// 256 threads; per-thread 4 rows x 8 cols. A staged transposed in LDS,
// B staged k-major. K chunked by 64.
// ---------------------------------------------------------------------------
template <int TN>
__global__ __launch_bounds__(256) void gemm_kernel(const float* __restrict__ A,
                                                   const float* __restrict__ B,
                                                   float* __restrict__ C, int M) {
    constexpr int K = 128;
    constexpr int KC = 64;
    constexpr int CG = TN / 8;        // col groups
    constexpr int TM = 1024 / CG;     // rows per block (64 or 128)
    constexpr int PAD = 4;

    __shared__ float At[KC][TM + PAD];  // [k][row]
    __shared__ float Bs[KC][TN + PAD];  // [k][col]

    int tid = threadIdx.x;
    int tx = tid % CG;
    int ty = tid / CG;
    int r  = ty * 4;            // local row base
    int c0 = tx * 4;            // first col slab
    int c1 = TN / 2 + tx * 4;   // second col slab
    int row0 = blockIdx.x * TM;

    float acc[4][8];
    #pragma unroll
    for (int i = 0; i < 4; i++)
        #pragma unroll
        for (int j = 0; j < 8; j++) acc[i][j] = 0.f;

    for (int kc = 0; kc < K; kc += KC) {
        __syncthreads();
        constexpr int AITEMS = TM * (KC / 4) / 256;
        #pragma unroll
        for (int it = 0; it < AITEMS; it++) {
            int idx = tid + it * 256;
            int row = idx / (KC / 4);
            int kq  = idx % (KC / 4);
            float4 av = make_float4(0.f, 0.f, 0.f, 0.f);
            int grow = row0 + row;
            if (grow < M)
                av = *(const float4*)(A + (size_t)grow * K + kc + kq * 4);
            At[kq * 4 + 0][row] = av.x;
            At[kq * 4 + 1][row] = av.y;
            At[kq * 4 + 2][row] = av.z;
            At[kq * 4 + 3][row] = av.w;
        }
        constexpr int BITEMS = KC * (TN / 4) / 256;
        #pragma unroll
        for (int it = 0; it < BITEMS; it++) {
            int idx = tid + it * 256;
            int kk = idx / (TN / 4);
            int c4 = idx % (TN / 4);
            float4 bv = *(const float4*)(B + (size_t)(kc + kk) * TN + c4 * 4);
            *(float4*)&Bs[kk][c4 * 4] = bv;
        }
        __syncthreads();

        #pragma unroll 8
        for (int kk = 0; kk < KC; kk++) {
            float4 a  = *(const float4*)&At[kk][r];
            float4 bA = *(const float4*)&Bs[kk][c0];
            float4 bB = *(const float4*)&Bs[kk][c1];
            float av[4]; av[0] = a.x; av[1] = a.y; av[2] = a.z; av[3] = a.w;
            float bv[8];
            bv[0] = bA.x; bv[1] = bA.y; bv[2] = bA.z; bv[3] = bA.w;
            bv[4] = bB.x; bv[5] = bB.y; bv[6] = bB.z; bv[7] = bB.w;
            #pragma unroll
            for (int i = 0; i < 4; i++)
                #pragma unroll
                for (int j = 0; j < 8; j++)
                    acc[i][j] += av[i] * bv[j];
        }
    }

    #pragma unroll
    for (int i = 0; i < 4; i++) {
        int grow = row0 + r + i;
        if (grow < M) {
            float4 v0 = make_float4(acc[i][0], acc[i][1], acc[i][2], acc[i][3]);
            float4 v1 = make_float4(acc[i][4], acc[i][5], acc[i][6], acc[i][7]);
            *(float4*)(C + (size_t)grow * TN + c0) = v0;
            *(float4*)(C + (size_t)grow * TN + c1) = v1;
        }
    }
}

// ---------------------------------------------------------------------------
// Pull-mode aggregation: out[n] = sum_{e: dst=n} h[src_e]*norm_e
//                                + h[n]*dinv[n]^2 + bias  (opt ReLU)
// One wave (64 threads) per node; each thread owns D/64 contiguous floats.
// ---------------------------------------------------------------------------
template <int D, bool RELU>
__global__ __launch_bounds__(64) void agg_kernel(const float* __restrict__ h,
                                                 const int* __restrict__ offs,
                                                 const int* __restrict__ csr_src,
                                                 const float* __restrict__ csr_norm,
                                                 const float* __restrict__ dinv,
                                                 const float* __restrict__ bias,
                                                 float* __restrict__ out, int n) {
    constexpr int V = D / 64;
    int node = blockIdx.x;
    int t = threadIdx.x;

    float di = dinv[node];
    float sw = di * di;
    const float* hp = h + (size_t)node * D + t * V;
    float acc[V];
    #pragma unroll
    for (int v = 0; v < V; v++) acc[v] = hp[v] * sw;

    int e0 = offs[node];
    int e1 = offs[node + 1];
    for (int e = e0; e < e1; e++) {
        int s = csr_src[e];
        float w = csr_norm[e];
        const float* hs = h + (size_t)s * D + t * V;
        #pragma unroll
        for (int v = 0; v < V; v++) acc[v] += hs[v] * w;
    }

    float* op = out + (size_t)node * D + t * V;
    #pragma unroll
    for (int v = 0; v < V; v++) {
        float rres = acc[v] + bias[t * V + v];
        if (RELU) rres = fmaxf(rres, 0.f);
        op[v] = rres;
    }
}

extern "C" void kernel_launch(void* const* d_in, const int* in_sizes, int n_in,
                              void* d_out, int out_size, void* d_ws, size_t ws_size,
                              hipStream_t stream) {
    const float* x  = (const float*)d_in[0];
    const int*   ei = (const int*)d_in[1];
    const float* W1 = (const float*)d_in[2];
    const float* b1 = (const float*)d_in[3];
    const float* W2 = (const float*)d_in[4];
    const float* b2 = (const float*)d_in[5];

    const int N = in_sizes[0] / 128;   // 50000
    const int E = in_sizes[1] / 2;     // 500000
    const int* src = ei;
    const int* dst = ei + E;

    char* p = (char*)d_ws;
    auto alloc = [&](size_t bytes) {
        char* r = p;
        p += (bytes + 255) & ~(size_t)255;
        return r;
    };
    int*   degi     = (int*)  alloc((size_t)N * 4);
    float* dinv     = (float*)alloc((size_t)N * 4);
    int*   offs     = (int*)  alloc((size_t)(N + 1) * 4);
    int*   cur      = (int*)  alloc((size_t)N * 4);
    int*   bsums    = (int*)  alloc((size_t)64 * 4);
    int*   csr_src  = (int*)  alloc((size_t)E * 4);
    float* csr_norm = (float*)alloc((size_t)E * 4);
    float* h1       = (float*)alloc((size_t)N * 128 * 4);
    float* hmid     = (float*)alloc((size_t)N * 128 * 4);
    float* h2       = h1;  // reuse: h1 dead after agg layer 1
    float* out      = (float*)d_out;

    const int NB = (N + 1023) / 1024;  // 49 <= 64

    // --- build degree / dinv / CSR (shared by both layers) ---
    hipMemsetAsync(degi, 0, (size_t)N * 4, stream);
    count_kernel<<<(E + 255) / 256, 256, 0, stream>>>(dst, E, degi);
    scanA_kernel<<<NB, 256, 0, stream>>>(degi, N, bsums);
    scanB_kernel<<<1, 64, 0, stream>>>(bsums, NB, offs + N);
    scanC_kernel<<<NB, 256, 0, stream>>>(degi, N, bsums, offs, cur, dinv);
    fill_kernel<<<(E + 255) / 256, 256, 0, stream>>>(src, dst, E, cur, dinv,
                                                     csr_src, csr_norm);

    // --- layer 1: h1 = x @ W1; hmid = relu(Agg(h1) + b1) ---
    gemm_kernel<128><<<(N + 63) / 64, 256, 0, stream>>>(x, W1, h1, N);
    agg_kernel<128, true><<<N, 64, 0, stream>>>(h1, offs, csr_src, csr_norm,
                                                dinv, b1, hmid, N);

    // --- layer 2: h2 = hmid @ W2; out = Agg(h2) + b2 ---
    gemm_kernel<64><<<(N + 127) / 128, 256, 0, stream>>>(hmid, W2, h2, N);
    agg_kernel<64, false><<<N, 64, 0, stream>>>(h2, offs, csr_src, csr_norm,
                                                dinv, b2, out, N);
}

// Round 3
// 244.386 us; speedup vs baseline: 1.2813x; 1.1102x over previous
//
#include <hip/hip_runtime.h>
#include <hip/hip_bf16.h>
#include <cstddef>

// ---------------------------------------------------------------------------
// 2-layer GCN: h1 = x@W1; hmid = relu(Agg(h1) + b1); h2 = hmid@W2;
// out = Agg(h2) + b2.  Agg = sym-normalized scatter-add with self-loops.
// R1: 3-phase multi-block scan (+fused dinv).
// R2: h1/h2 stored bf16 (halves agg gather bytes), CSR packed int2,
//     edge loop unrolled x4, 4 nodes per 256-thread agg block.
// ---------------------------------------------------------------------------

__device__ inline unsigned short f2bf(float f) {
    __hip_bfloat16 b = __float2bfloat16(f);
    return *reinterpret_cast<unsigned short*>(&b);
}
__device__ inline float bf2f_lo(unsigned int u) {
    unsigned int v = u << 16;
    return *reinterpret_cast<float*>(&v);
}
__device__ inline float bf2f_hi(unsigned int u) {
    unsigned int v = u & 0xffff0000u;
    return *reinterpret_cast<float*>(&v);
}

__global__ __launch_bounds__(256) void count_kernel(const int* __restrict__ dst, int E,
                                                    int* __restrict__ deg) {
    int i = blockIdx.x * blockDim.x + threadIdx.x;
    if (i < E) atomicAdd(&deg[dst[i]], 1);
}

// ---- 3-phase exclusive scan over deg[0..n) ; chunk = 1024 elems/block ----
__global__ __launch_bounds__(256) void scanA_kernel(const int* __restrict__ deg, int n,
                                                    int* __restrict__ bsums) {
    int tid = threadIdx.x;
    int lane = tid & 63;
    int wid = tid >> 6;
    int i = blockIdx.x * 1024 + tid * 4;
    int v0 = (i + 0 < n) ? deg[i + 0] : 0;
    int v1 = (i + 1 < n) ? deg[i + 1] : 0;
    int v2 = (i + 2 < n) ? deg[i + 2] : 0;
    int v3 = (i + 3 < n) ? deg[i + 3] : 0;
    int s = v0 + v1 + v2 + v3;
    #pragma unroll
    for (int off = 32; off > 0; off >>= 1) s += __shfl_down(s, off, 64);
    __shared__ int ws[4];
    if (lane == 0) ws[wid] = s;
    __syncthreads();
    if (tid == 0) bsums[blockIdx.x] = ws[0] + ws[1] + ws[2] + ws[3];
}

__global__ __launch_bounds__(64) void scanB_kernel(int* __restrict__ bsums, int nb,
                                                   int* __restrict__ totp) {
    int lane = threadIdx.x;
    int v = (lane < nb) ? bsums[lane] : 0;
    int x = v;
    #pragma unroll
    for (int off = 1; off < 64; off <<= 1) {
        int y = __shfl_up(x, off, 64);
        if (lane >= off) x += y;
    }
    if (lane < nb) bsums[lane] = x - v;   // exclusive
    if (lane == 63) *totp = x;
}

__global__ __launch_bounds__(256) void scanC_kernel(const int* __restrict__ deg, int n,
                                                    const int* __restrict__ bsums,
                                                    int* __restrict__ offs,
                                                    int* __restrict__ cur,
                                                    float* __restrict__ dinv) {
    int tid = threadIdx.x;
    int lane = tid & 63;
    int wid = tid >> 6;
    int carry = bsums[blockIdx.x];
    int i = blockIdx.x * 1024 + tid * 4;
    int v0 = (i + 0 < n) ? deg[i + 0] : 0;
    int v1 = (i + 1 < n) ? deg[i + 1] : 0;
    int v2 = (i + 2 < n) ? deg[i + 2] : 0;
    int v3 = (i + 3 < n) ? deg[i + 3] : 0;
    int t = v0 + v1 + v2 + v3;
    int x = t;
    #pragma unroll
    for (int off = 1; off < 64; off <<= 1) {
        int y = __shfl_up(x, off, 64);
        if (lane >= off) x += y;
    }
    __shared__ int ws[4];
    if (lane == 63) ws[wid] = x;
    __syncthreads();
    int wprefix = 0;
    #pragma unroll
    for (int w = 0; w < 4; w++) wprefix += (w < wid) ? ws[w] : 0;
    int e0 = carry + wprefix + x - t;
    int e1 = e0 + v0, e2 = e1 + v1, e3 = e2 + v2;
    if (i + 0 < n) { offs[i + 0] = e0; cur[i + 0] = e0; dinv[i + 0] = rsqrtf((float)(v0 + 1)); }
    if (i + 1 < n) { offs[i + 1] = e1; cur[i + 1] = e1; dinv[i + 1] = rsqrtf((float)(v1 + 1)); }
    if (i + 2 < n) { offs[i + 2] = e2; cur[i + 2] = e2; dinv[i + 2] = rsqrtf((float)(v2 + 1)); }
    if (i + 3 < n) { offs[i + 3] = e3; cur[i + 3] = e3; dinv[i + 3] = rsqrtf((float)(v3 + 1)); }
}

// CSR fill: packed {src, norm-bits} per edge
__global__ __launch_bounds__(256) void fill_kernel(const int* __restrict__ src,
                                                   const int* __restrict__ dst, int E,
                                                   int* __restrict__ cur,
                                                   const float* __restrict__ dinv,
                                                   int2* __restrict__ csr_pack) {
    int i = blockIdx.x * blockDim.x + threadIdx.x;
    if (i < E) {
        int s = src[i];
        int d = dst[i];
        int p = atomicAdd(&cur[d], 1);
        float w = dinv[s] * dinv[d];
        csr_pack[p] = make_int2(s, __float_as_int(w));
    }
}

// ---------------------------------------------------------------------------
// fp32 GEMM: C[M, TN] = A[M,128] @ B[128,TN], C stored bf16.
// ---------------------------------------------------------------------------
template <int TN>
__global__ __launch_bounds__(256) void gemm_kernel(const float* __restrict__ A,
                                                   const float* __restrict__ B,
                                                   unsigned short* __restrict__ C,
                                                   int M) {
    constexpr int K = 128;
    constexpr int KC = 64;
    constexpr int CG = TN / 8;
    constexpr int TM = 1024 / CG;
    constexpr int PAD = 4;

    __shared__ float At[KC][TM + PAD];
    __shared__ float Bs[KC][TN + PAD];

    int tid = threadIdx.x;
    int tx = tid % CG;
    int ty = tid / CG;
    int r  = ty * 4;
    int c0 = tx * 4;
    int c1 = TN / 2 + tx * 4;
    int row0 = blockIdx.x * TM;

    float acc[4][8];
    #pragma unroll
    for (int i = 0; i < 4; i++)
        #pragma unroll
        for (int j = 0; j < 8; j++) acc[i][j] = 0.f;

    for (int kc = 0; kc < K; kc += KC) {
        __syncthreads();
        constexpr int AITEMS = TM * (KC / 4) / 256;
        #pragma unroll
        for (int it = 0; it < AITEMS; it++) {
            int idx = tid + it * 256;
            int row = idx / (KC / 4);
            int kq  = idx % (KC / 4);
            float4 av = make_float4(0.f, 0.f, 0.f, 0.f);
            int grow = row0 + row;
            if (grow < M)
                av = *(const float4*)(A + (size_t)grow * K + kc + kq * 4);
            At[kq * 4 + 0][row] = av.x;
            At[kq * 4 + 1][row] = av.y;
            At[kq * 4 + 2][row] = av.z;
            At[kq * 4 + 3][row] = av.w;
        }
        constexpr int BITEMS = KC * (TN / 4) / 256;
        #pragma unroll
        for (int it = 0; it < BITEMS; it++) {
            int idx = tid + it * 256;
            int kk = idx / (TN / 4);
            int c4 = idx % (TN / 4);
            float4 bv = *(const float4*)(B + (size_t)(kc + kk) * TN + c4 * 4);
            *(float4*)&Bs[kk][c4 * 4] = bv;
        }
        __syncthreads();

        #pragma unroll 8
        for (int kk = 0; kk < KC; kk++) {
            float4 a  = *(const float4*)&At[kk][r];
            float4 bA = *(const float4*)&Bs[kk][c0];
            float4 bB = *(const float4*)&Bs[kk][c1];
            float av[4]; av[0] = a.x; av[1] = a.y; av[2] = a.z; av[3] = a.w;
            float bv[8];
            bv[0] = bA.x; bv[1] = bA.y; bv[2] = bA.z; bv[3] = bA.w;
            bv[4] = bB.x; bv[5] = bB.y; bv[6] = bB.z; bv[7] = bB.w;
            #pragma unroll
            for (int i = 0; i < 4; i++)
                #pragma unroll
                for (int j = 0; j < 8; j++)
                    acc[i][j] += av[i] * bv[j];
        }
    }

    #pragma unroll
    for (int i = 0; i < 4; i++) {
        int grow = row0 + r + i;
        if (grow < M) {
            ushort4 o0, o1;
            o0.x = f2bf(acc[i][0]); o0.y = f2bf(acc[i][1]);
            o0.z = f2bf(acc[i][2]); o0.w = f2bf(acc[i][3]);
            o1.x = f2bf(acc[i][4]); o1.y = f2bf(acc[i][5]);
            o1.z = f2bf(acc[i][6]); o1.w = f2bf(acc[i][7]);
            *(ushort4*)(C + (size_t)grow * TN + c0) = o0;
            *(ushort4*)(C + (size_t)grow * TN + c1) = o1;
        }
    }
}

// ---------------------------------------------------------------------------
// Pull-mode aggregation, bf16 h -> fp32 out.
// 4 waves per block, one node per wave. Edge loop unrolled x4.
// ---------------------------------------------------------------------------
template <int D, bool RELU>
__global__ __launch_bounds__(256) void agg_kernel(const unsigned short* __restrict__ h,
                                                  const int* __restrict__ offs,
                                                  const int2* __restrict__ csr_pack,
                                                  const float* __restrict__ dinv,
                                                  const float* __restrict__ bias,
                                                  float* __restrict__ out, int n) {
    constexpr int V = D / 64;   // bf16 elems per thread (2 for D=128, 1 for D=64)
    int wid = threadIdx.x >> 6;
    int t = threadIdx.x & 63;
    int node = blockIdx.x * 4 + wid;
    if (node >= n) return;

    float di = dinv[node];
    float sw = di * di;

    float acc0 = 0.f, acc1 = 0.f;
    // self loop
    if constexpr (V == 2) {
        unsigned int u = *(const unsigned int*)(h + (size_t)node * D + t * 2);
        acc0 = bf2f_lo(u) * sw;
        acc1 = bf2f_hi(u) * sw;
    } else {
        unsigned int u = h[(size_t)node * D + t];
        acc0 = bf2f_lo(u) * sw;
    }

    int e0 = offs[node];
    int e1 = offs[node + 1];
    int e = e0;
    for (; e + 4 <= e1; e += 4) {
        int2 p0 = csr_pack[e + 0];
        int2 p1 = csr_pack[e + 1];
        int2 p2 = csr_pack[e + 2];
        int2 p3 = csr_pack[e + 3];
        float w0 = __int_as_float(p0.y), w1 = __int_as_float(p1.y);
        float w2 = __int_as_float(p2.y), w3 = __int_as_float(p3.y);
        if constexpr (V == 2) {
            unsigned int u0 = *(const unsigned int*)(h + (size_t)p0.x * D + t * 2);
            unsigned int u1 = *(const unsigned int*)(h + (size_t)p1.x * D + t * 2);
            unsigned int u2 = *(const unsigned int*)(h + (size_t)p2.x * D + t * 2);
            unsigned int u3 = *(const unsigned int*)(h + (size_t)p3.x * D + t * 2);
            acc0 += bf2f_lo(u0) * w0; acc1 += bf2f_hi(u0) * w0;
            acc0 += bf2f_lo(u1) * w1; acc1 += bf2f_hi(u1) * w1;
            acc0 += bf2f_lo(u2) * w2; acc1 += bf2f_hi(u2) * w2;
            acc0 += bf2f_lo(u3) * w3; acc1 += bf2f_hi(u3) * w3;
        } else {
            unsigned int u0 = h[(size_t)p0.x * D + t];
            unsigned int u1 = h[(size_t)p1.x * D + t];
            unsigned int u2 = h[(size_t)p2.x * D + t];
            unsigned int u3 = h[(size_t)p3.x * D + t];
            acc0 += bf2f_lo(u0) * w0;
            acc0 += bf2f_lo(u1) * w1;
            acc0 += bf2f_lo(u2) * w2;
            acc0 += bf2f_lo(u3) * w3;
        }
    }
    for (; e < e1; e++) {
        int2 p = csr_pack[e];
        float w = __int_as_float(p.y);
        if constexpr (V == 2) {
            unsigned int u = *(const unsigned int*)(h + (size_t)p.x * D + t * 2);
            acc0 += bf2f_lo(u) * w; acc1 += bf2f_hi(u) * w;
        } else {
            unsigned int u = h[(size_t)p.x * D + t];
            acc0 += bf2f_lo(u) * w;
        }
    }

    float* op = out + (size_t)node * D + t * V;
    if constexpr (V == 2) {
        float r0 = acc0 + bias[t * 2 + 0];
        float r1 = acc1 + bias[t * 2 + 1];
        if (RELU) { r0 = fmaxf(r0, 0.f); r1 = fmaxf(r1, 0.f); }
        *(float2*)op = make_float2(r0, r1);
    } else {
        float r0 = acc0 + bias[t];
        if (RELU) r0 = fmaxf(r0, 0.f);
        *op = r0;
    }
}

extern "C" void kernel_launch(void* const* d_in, const int* in_sizes, int n_in,
                              void* d_out, int out_size, void* d_ws, size_t ws_size,
                              hipStream_t stream) {
    const float* x  = (const float*)d_in[0];
    const int*   ei = (const int*)d_in[1];
    const float* W1 = (const float*)d_in[2];
    const float* b1 = (const float*)d_in[3];
    const float* W2 = (const float*)d_in[4];
    const float* b2 = (const float*)d_in[5];

    const int N = in_sizes[0] / 128;   // 50000
    const int E = in_sizes[1] / 2;     // 500000
    const int* src = ei;
    const int* dst = ei + E;

    char* p = (char*)d_ws;
    auto alloc = [&](size_t bytes) {
        char* r = p;
        p += (bytes + 255) & ~(size_t)255;
        return r;
    };
    int*   degi     = (int*)  alloc((size_t)N * 4);
    float* dinv     = (float*)alloc((size_t)N * 4);
    int*   offs     = (int*)  alloc((size_t)(N + 1) * 4);
    int*   cur      = (int*)  alloc((size_t)N * 4);
    int*   bsums    = (int*)  alloc((size_t)64 * 4);
    int2*  csr_pack = (int2*) alloc((size_t)E * 8);
    unsigned short* h1   = (unsigned short*)alloc((size_t)N * 128 * 2);  // bf16
    float*          hmid = (float*)alloc((size_t)N * 128 * 4);
    unsigned short* h2   = h1;  // reuse: h1 dead after agg layer 1
    float* out      = (float*)d_out;

    const int NB = (N + 1023) / 1024;  // 49 <= 64

    // --- build degree / dinv / CSR (shared by both layers) ---
    hipMemsetAsync(degi, 0, (size_t)N * 4, stream);
    count_kernel<<<(E + 255) / 256, 256, 0, stream>>>(dst, E, degi);
    scanA_kernel<<<NB, 256, 0, stream>>>(degi, N, bsums);
    scanB_kernel<<<1, 64, 0, stream>>>(bsums, NB, offs + N);
    scanC_kernel<<<NB, 256, 0, stream>>>(degi, N, bsums, offs, cur, dinv);
    fill_kernel<<<(E + 255) / 256, 256, 0, stream>>>(src, dst, E, cur, dinv, csr_pack);

    // --- layer 1: h1 = x @ W1 (bf16); hmid = relu(Agg(h1) + b1) (fp32) ---
    gemm_kernel<128><<<(N + 63) / 64, 256, 0, stream>>>(x, W1, h1, N);
    agg_kernel<128, true><<<(N + 3) / 4, 256, 0, stream>>>(h1, offs, csr_pack,
                                                           dinv, b1, hmid, N);

    // --- layer 2: h2 = hmid @ W2 (bf16); out = Agg(h2) + b2 ---
    gemm_kernel<64><<<(N + 127) / 128, 256, 0, stream>>>(hmid, W2, h2, N);
    agg_kernel<64, false><<<(N + 3) / 4, 256, 0, stream>>>(h2, offs, csr_pack,
                                                           dinv, b2, out, N);
}

// Round 4
// 216.530 us; speedup vs baseline: 1.4462x; 1.1286x over previous
//
#include <hip/hip_runtime.h>
#include <hip/hip_bf16.h>
#include <cstddef>

// ---------------------------------------------------------------------------
// 2-layer GCN: h1 = x@W1; hmid = relu(Agg(h1) + b1); h2 = hmid@W2;
// out = Agg(h2) + b2.  Agg = sym-normalized scatter-add with self-loops.
// R1: 3-phase multi-block scan (+fused dinv).
// R2: h1/h2 stored bf16, CSR packed int2, agg unroll x4, 4 waves/block.
// R3: GEMMs -> MFMA bf16 (16x16x32), fp32->bf16 cast fused into staging,
//     W pre-transposed, LDS in fragment order (conflict-free b128),
//     hmid stored bf16.
// ---------------------------------------------------------------------------

typedef __attribute__((ext_vector_type(8))) short short8;
typedef __attribute__((ext_vector_type(4))) float f32x4;

__device__ inline unsigned short f2bf(float f) {
    __hip_bfloat16 b = __float2bfloat16(f);
    return *reinterpret_cast<unsigned short*>(&b);
}
__device__ inline float bf2f_lo(unsigned int u) {
    unsigned int v = u << 16;
    return *reinterpret_cast<float*>(&v);
}
__device__ inline float bf2f_hi(unsigned int u) {
    unsigned int v = u & 0xffff0000u;
    return *reinterpret_cast<float*>(&v);
}

__global__ __launch_bounds__(256) void count_kernel(const int* __restrict__ dst, int E,
                                                    int* __restrict__ deg) {
    int i = blockIdx.x * blockDim.x + threadIdx.x;
    if (i < E) atomicAdd(&deg[dst[i]], 1);
}

// ---- 3-phase exclusive scan over deg[0..n) ----
__global__ __launch_bounds__(256) void scanA_kernel(const int* __restrict__ deg, int n,
                                                    int* __restrict__ bsums) {
    int tid = threadIdx.x;
    int lane = tid & 63;
    int wid = tid >> 6;
    int i = blockIdx.x * 1024 + tid * 4;
    int v0 = (i + 0 < n) ? deg[i + 0] : 0;
    int v1 = (i + 1 < n) ? deg[i + 1] : 0;
    int v2 = (i + 2 < n) ? deg[i + 2] : 0;
    int v3 = (i + 3 < n) ? deg[i + 3] : 0;
    int s = v0 + v1 + v2 + v3;
    #pragma unroll
    for (int off = 32; off > 0; off >>= 1) s += __shfl_down(s, off, 64);
    __shared__ int ws[4];
    if (lane == 0) ws[wid] = s;
    __syncthreads();
    if (tid == 0) bsums[blockIdx.x] = ws[0] + ws[1] + ws[2] + ws[3];
}

__global__ __launch_bounds__(64) void scanB_kernel(int* __restrict__ bsums, int nb,
                                                   int* __restrict__ totp) {
    int lane = threadIdx.x;
    int v = (lane < nb) ? bsums[lane] : 0;
    int x = v;
    #pragma unroll
    for (int off = 1; off < 64; off <<= 1) {
        int y = __shfl_up(x, off, 64);
        if (lane >= off) x += y;
    }
    if (lane < nb) bsums[lane] = x - v;
    if (lane == 63) *totp = x;
}

__global__ __launch_bounds__(256) void scanC_kernel(const int* __restrict__ deg, int n,
                                                    const int* __restrict__ bsums,
                                                    int* __restrict__ offs,
                                                    int* __restrict__ cur,
                                                    float* __restrict__ dinv) {
    int tid = threadIdx.x;
    int lane = tid & 63;
    int wid = tid >> 6;
    int carry = bsums[blockIdx.x];
    int i = blockIdx.x * 1024 + tid * 4;
    int v0 = (i + 0 < n) ? deg[i + 0] : 0;
    int v1 = (i + 1 < n) ? deg[i + 1] : 0;
    int v2 = (i + 2 < n) ? deg[i + 2] : 0;
    int v3 = (i + 3 < n) ? deg[i + 3] : 0;
    int t = v0 + v1 + v2 + v3;
    int x = t;
    #pragma unroll
    for (int off = 1; off < 64; off <<= 1) {
        int y = __shfl_up(x, off, 64);
        if (lane >= off) x += y;
    }
    __shared__ int ws[4];
    if (lane == 63) ws[wid] = x;
    __syncthreads();
    int wprefix = 0;
    #pragma unroll
    for (int w = 0; w < 4; w++) wprefix += (w < wid) ? ws[w] : 0;
    int e0 = carry + wprefix + x - t;
    int e1 = e0 + v0, e2 = e1 + v1, e3 = e2 + v2;
    if (i + 0 < n) { offs[i + 0] = e0; cur[i + 0] = e0; dinv[i + 0] = rsqrtf((float)(v0 + 1)); }
    if (i + 1 < n) { offs[i + 1] = e1; cur[i + 1] = e1; dinv[i + 1] = rsqrtf((float)(v1 + 1)); }
    if (i + 2 < n) { offs[i + 2] = e2; cur[i + 2] = e2; dinv[i + 2] = rsqrtf((float)(v2 + 1)); }
    if (i + 3 < n) { offs[i + 3] = e3; cur[i + 3] = e3; dinv[i + 3] = rsqrtf((float)(v3 + 1)); }
}

__global__ __launch_bounds__(256) void fill_kernel(const int* __restrict__ src,
                                                   const int* __restrict__ dst, int E,
                                                   int* __restrict__ cur,
                                                   const float* __restrict__ dinv,
                                                   int2* __restrict__ csr_pack) {
    int i = blockIdx.x * blockDim.x + threadIdx.x;
    if (i < E) {
        int s = src[i];
        int d = dst[i];
        int p = atomicAdd(&cur[d], 1);
        float w = dinv[s] * dinv[d];
        csr_pack[p] = make_int2(s, __float_as_int(w));
    }
}

// W [K][N] fp32 -> Wt [N][K] bf16
__global__ __launch_bounds__(256) void wt_kernel(const float* __restrict__ W,
                                                 unsigned short* __restrict__ Wt,
                                                 int K, int N) {
    int i = blockIdx.x * 256 + threadIdx.x;
    if (i < K * N) {
        int k = i / N, n = i % N;
        Wt[n * K + k] = f2bf(W[i]);
    }
}

// ---------------------------------------------------------------------------
// MFMA bf16 GEMM: C[M, BN] = A[M,128] @ W[128,BN], C bf16.
// A fp32 (cast in staging) or bf16. Wt pre-transposed [BN][128] bf16.
// Block: 256 thr, tile BM=64 x BN, K=128 single shot.
// LDS in MFMA fragment order: frag(tile, ks) at [(tile*4+ks)*64 + lane]*8
// -> every ds_read_b128 is wave-contiguous 1024B (conflict-free).
// ---------------------------------------------------------------------------
template <int BN, bool ABF16>
__global__ __launch_bounds__(256) void mfma_gemm_kernel(const void* __restrict__ Av,
                                                        const unsigned short* __restrict__ Wt,
                                                        unsigned short* __restrict__ C,
                                                        int M) {
    constexpr int BM = 64;
    constexpr int K = 128;
    constexpr int NT = BN / 16;    // n-tiles total (8 or 4)
    constexpr int NTW = NT / 4;    // n-tiles per wave (2 or 1)

    __shared__ unsigned short As[BM * K];  // 16 KB
    __shared__ unsigned short Bs[BN * K];  // 32 or 16 KB

    int tid = threadIdx.x;
    int lane = tid & 63;
    int w = tid >> 6;
    int row0 = blockIdx.x * BM;

    // --- stage B (Wt[n][k] bf16 -> fragment order) ---
    #pragma unroll
    for (int it = 0; it < BN / 16; it++) {
        int idx = it * 256 + tid;
        int n = idx >> 4, kc = idx & 15;
        int k0 = kc * 8;
        int ks = k0 >> 5, quad = (k0 >> 3) & 3;
        int ntg = n >> 4;
        short8 v = *(const short8*)(Wt + (size_t)n * K + k0);
        int off = (((ntg * 4 + ks) * 64) + (n & 15) + 16 * quad) * 8;
        *(short8*)(Bs + off) = v;
    }
    // --- stage A ---
    if (ABF16) {
        const unsigned short* A = (const unsigned short*)Av;
        #pragma unroll
        for (int it = 0; it < 4; it++) {
            int idx = it * 256 + tid;
            int row = idx >> 4, kc = idx & 15;
            int k0 = kc * 8;
            int ks = k0 >> 5, quad = (k0 >> 3) & 3, mt = row >> 4;
            short8 v = {};
            int gr = row0 + row;
            if (gr < M) v = *(const short8*)(A + (size_t)gr * K + k0);
            int off = (((mt * 4 + ks) * 64) + (row & 15) + 16 * quad) * 8;
            *(short8*)(As + off) = v;
        }
    } else {
        const float* A = (const float*)Av;
        #pragma unroll
        for (int it = 0; it < 8; it++) {
            int idx = it * 256 + tid;
            int row = idx >> 5, kq = idx & 31;
            int k0 = kq * 4;
            int ks = k0 >> 5, quad = (k0 >> 3) & 3, j0 = k0 & 7, mt = row >> 4;
            ushort4 o = make_ushort4(0, 0, 0, 0);
            int gr = row0 + row;
            if (gr < M) {
                float4 a = *(const float4*)(A + (size_t)gr * K + k0);
                o.x = f2bf(a.x); o.y = f2bf(a.y); o.z = f2bf(a.z); o.w = f2bf(a.w);
            }
            int off = (((mt * 4 + ks) * 64) + (row & 15) + 16 * quad) * 8 + j0;
            *(ushort4*)(As + off) = o;
        }
    }
    __syncthreads();

    // --- compute: wave w covers n-tiles [w*NTW, w*NTW+NTW), all 4 m-tiles ---
    f32x4 acc[4][NTW];
    #pragma unroll
    for (int mt = 0; mt < 4; mt++)
        #pragma unroll
        for (int nl = 0; nl < NTW; nl++)
            acc[mt][nl] = (f32x4){0.f, 0.f, 0.f, 0.f};

    #pragma unroll
    for (int ks = 0; ks < 4; ks++) {
        short8 af[4], bf[NTW];
        #pragma unroll
        for (int mt = 0; mt < 4; mt++)
            af[mt] = *(const short8*)(As + (((mt * 4 + ks) * 64) + lane) * 8);
        #pragma unroll
        for (int nl = 0; nl < NTW; nl++) {
            int ntg = w * NTW + nl;
            bf[nl] = *(const short8*)(Bs + (((ntg * 4 + ks) * 64) + lane) * 8);
        }
        #pragma unroll
        for (int mt = 0; mt < 4; mt++)
            #pragma unroll
            for (int nl = 0; nl < NTW; nl++)
                acc[mt][nl] = __builtin_amdgcn_mfma_f32_16x16x32_bf16(
                    af[mt], bf[nl], acc[mt][nl], 0, 0, 0);
    }

    // --- epilogue: C/D layout col=lane&15, row=(lane>>4)*4+reg ---
    int col16 = lane & 15;
    int rowq = lane >> 4;
    #pragma unroll
    for (int mt = 0; mt < 4; mt++) {
        #pragma unroll
        for (int nl = 0; nl < NTW; nl++) {
            int gc = (w * NTW + nl) * 16 + col16;
            #pragma unroll
            for (int r = 0; r < 4; r++) {
                int gr = row0 + mt * 16 + rowq * 4 + r;
                if (gr < M) C[(size_t)gr * BN + gc] = f2bf(acc[mt][nl][r]);
            }
        }
    }
}

// ---------------------------------------------------------------------------
// Pull-mode aggregation, bf16 h -> fp32 or bf16 out.
// 4 waves per block, one node per wave. Edge loop unrolled x4.
// ---------------------------------------------------------------------------
template <int D, bool RELU, bool OUTBF>
__global__ __launch_bounds__(256) void agg_kernel(const unsigned short* __restrict__ h,
                                                  const int* __restrict__ offs,
                                                  const int2* __restrict__ csr_pack,
                                                  const float* __restrict__ dinv,
                                                  const float* __restrict__ bias,
                                                  void* __restrict__ outv, int n) {
    constexpr int V = D / 64;
    int wid = threadIdx.x >> 6;
    int t = threadIdx.x & 63;
    int node = blockIdx.x * 4 + wid;
    if (node >= n) return;

    float di = dinv[node];
    float sw = di * di;

    float acc0 = 0.f, acc1 = 0.f;
    if constexpr (V == 2) {
        unsigned int u = *(const unsigned int*)(h + (size_t)node * D + t * 2);
        acc0 = bf2f_lo(u) * sw;
        acc1 = bf2f_hi(u) * sw;
    } else {
        unsigned int u = h[(size_t)node * D + t];
        acc0 = bf2f_lo(u) * sw;
    }

    int e0 = offs[node];
    int e1 = offs[node + 1];
    int e = e0;
    for (; e + 4 <= e1; e += 4) {
        int2 p0 = csr_pack[e + 0];
        int2 p1 = csr_pack[e + 1];
        int2 p2 = csr_pack[e + 2];
        int2 p3 = csr_pack[e + 3];
        float w0 = __int_as_float(p0.y), w1 = __int_as_float(p1.y);
        float w2 = __int_as_float(p2.y), w3 = __int_as_float(p3.y);
        if constexpr (V == 2) {
            unsigned int u0 = *(const unsigned int*)(h + (size_t)p0.x * D + t * 2);
            unsigned int u1 = *(const unsigned int*)(h + (size_t)p1.x * D + t * 2);
            unsigned int u2 = *(const unsigned int*)(h + (size_t)p2.x * D + t * 2);
            unsigned int u3 = *(const unsigned int*)(h + (size_t)p3.x * D + t * 2);
            acc0 += bf2f_lo(u0) * w0; acc1 += bf2f_hi(u0) * w0;
            acc0 += bf2f_lo(u1) * w1; acc1 += bf2f_hi(u1) * w1;
            acc0 += bf2f_lo(u2) * w2; acc1 += bf2f_hi(u2) * w2;
            acc0 += bf2f_lo(u3) * w3; acc1 += bf2f_hi(u3) * w3;
        } else {
            unsigned int u0 = h[(size_t)p0.x * D + t];
            unsigned int u1 = h[(size_t)p1.x * D + t];
            unsigned int u2 = h[(size_t)p2.x * D + t];
            unsigned int u3 = h[(size_t)p3.x * D + t];
            acc0 += bf2f_lo(u0) * w0;
            acc0 += bf2f_lo(u1) * w1;
            acc0 += bf2f_lo(u2) * w2;
            acc0 += bf2f_lo(u3) * w3;
        }
    }
    for (; e < e1; e++) {
        int2 p = csr_pack[e];
        float w = __int_as_float(p.y);
        if constexpr (V == 2) {
            unsigned int u = *(const unsigned int*)(h + (size_t)p.x * D + t * 2);
            acc0 += bf2f_lo(u) * w; acc1 += bf2f_hi(u) * w;
        } else {
            unsigned int u = h[(size_t)p.x * D + t];
            acc0 += bf2f_lo(u) * w;
        }
    }

    if constexpr (V == 2) {
        float r0 = acc0 + bias[t * 2 + 0];
        float r1 = acc1 + bias[t * 2 + 1];
        if (RELU) { r0 = fmaxf(r0, 0.f); r1 = fmaxf(r1, 0.f); }
        if constexpr (OUTBF) {
            unsigned int pack = (unsigned int)f2bf(r0) | ((unsigned int)f2bf(r1) << 16);
            *(unsigned int*)((unsigned short*)outv + (size_t)node * D + t * 2) = pack;
        } else {
            *(float2*)((float*)outv + (size_t)node * D + t * 2) = make_float2(r0, r1);
        }
    } else {
        float r0 = acc0 + bias[t];
        if (RELU) r0 = fmaxf(r0, 0.f);
        if constexpr (OUTBF) {
            ((unsigned short*)outv)[(size_t)node * D + t] = f2bf(r0);
        } else {
            ((float*)outv)[(size_t)node * D + t] = r0;
        }
    }
}

extern "C" void kernel_launch(void* const* d_in, const int* in_sizes, int n_in,
                              void* d_out, int out_size, void* d_ws, size_t ws_size,
                              hipStream_t stream) {
    const float* x  = (const float*)d_in[0];
    const int*   ei = (const int*)d_in[1];
    const float* W1 = (const float*)d_in[2];
    const float* b1 = (const float*)d_in[3];
    const float* W2 = (const float*)d_in[4];
    const float* b2 = (const float*)d_in[5];

    const int N = in_sizes[0] / 128;   // 50000
    const int E = in_sizes[1] / 2;     // 500000
    const int* src = ei;
    const int* dst = ei + E;

    char* p = (char*)d_ws;
    auto alloc = [&](size_t bytes) {
        char* r = p;
        p += (bytes + 255) & ~(size_t)255;
        return r;
    };
    int*   degi     = (int*)  alloc((size_t)N * 4);
    float* dinv     = (float*)alloc((size_t)N * 4);
    int*   offs     = (int*)  alloc((size_t)(N + 1) * 4);
    int*   cur      = (int*)  alloc((size_t)N * 4);
    int*   bsums    = (int*)  alloc((size_t)64 * 4);
    int2*  csr_pack = (int2*) alloc((size_t)E * 8);
    unsigned short* Wt1  = (unsigned short*)alloc((size_t)128 * 128 * 2);
    unsigned short* Wt2  = (unsigned short*)alloc((size_t)64 * 128 * 2);
    unsigned short* h1   = (unsigned short*)alloc((size_t)N * 128 * 2);  // bf16
    unsigned short* hmid = (unsigned short*)alloc((size_t)N * 128 * 2);  // bf16
    unsigned short* h2   = h1;  // reuse: h1 dead after agg layer 1
    float* out      = (float*)d_out;

    const int NB = (N + 1023) / 1024;  // 49 <= 64

    // --- build degree / dinv / CSR (shared by both layers) + W transposes ---
    hipMemsetAsync(degi, 0, (size_t)N * 4, stream);
    count_kernel<<<(E + 255) / 256, 256, 0, stream>>>(dst, E, degi);
    wt_kernel<<<(128 * 128 + 255) / 256, 256, 0, stream>>>(W1, Wt1, 128, 128);
    wt_kernel<<<(128 * 64 + 255) / 256, 256, 0, stream>>>(W2, Wt2, 128, 64);
    scanA_kernel<<<NB, 256, 0, stream>>>(degi, N, bsums);
    scanB_kernel<<<1, 64, 0, stream>>>(bsums, NB, offs + N);
    scanC_kernel<<<NB, 256, 0, stream>>>(degi, N, bsums, offs, cur, dinv);
    fill_kernel<<<(E + 255) / 256, 256, 0, stream>>>(src, dst, E, cur, dinv, csr_pack);

    const int GB = (N + 63) / 64;  // 782 gemm blocks

    // --- layer 1: h1 = x @ W1 (bf16); hmid = relu(Agg(h1) + b1) (bf16) ---
    mfma_gemm_kernel<128, false><<<GB, 256, 0, stream>>>(x, Wt1, h1, N);
    agg_kernel<128, true, true><<<(N + 3) / 4, 256, 0, stream>>>(h1, offs, csr_pack,
                                                                 dinv, b1, hmid, N);

    // --- layer 2: h2 = hmid @ W2 (bf16); out = Agg(h2) + b2 (fp32) ---
    mfma_gemm_kernel<64, true><<<GB, 256, 0, stream>>>(hmid, Wt2, h2, N);
    agg_kernel<64, false, false><<<(N + 3) / 4, 256, 0, stream>>>(h2, offs, csr_pack,
                                                                  dinv, b2, out, N);
}

// Round 5
// 197.730 us; speedup vs baseline: 1.5837x; 1.0951x over previous
//
#include <hip/hip_runtime.h>
#include <hip/hip_bf16.h>
#include <cstddef>

// ---------------------------------------------------------------------------
// 2-layer GCN: h1 = x@W1; hmid = relu(Agg(h1) + b1); h2 = hmid@W2;
// out = Agg(h2) + b2.  Agg = sym-normalized scatter-add with self-loops.
// R1: 3-phase multi-block scan (+fused dinv).
// R2: h1/h2 bf16, agg unroll x4, 4 waves/block.
// R3: MFMA bf16 GEMMs, fragment-order LDS, hmid bf16.
// R4: CSR packed to 4 B/edge (src16 | bf16norm), weights pre-laid in global
//     MFMA fragment order, gemm2 fused into agg1 (aggmm: 16 nodes/block,
//     LDS A-frags -> 4 MFMAs/wave), agg2 2-edges-per-wave with 4B loads,
//     branchless padded edge loops.
// ---------------------------------------------------------------------------

typedef __attribute__((ext_vector_type(8))) short short8;
typedef __attribute__((ext_vector_type(4))) float f32x4;

__device__ inline unsigned short f2bf(float f) {
    __hip_bfloat16 b = __float2bfloat16(f);
    return *reinterpret_cast<unsigned short*>(&b);
}
__device__ inline float bf2f_lo(unsigned int u) {
    unsigned int v = u << 16;
    return *reinterpret_cast<float*>(&v);
}
__device__ inline float bf2f_hi(unsigned int u) {
    unsigned int v = u & 0xffff0000u;
    return *reinterpret_cast<float*>(&v);
}

__global__ __launch_bounds__(256) void count_kernel(const int* __restrict__ dst, int E,
                                                    int* __restrict__ deg) {
    int i = blockIdx.x * blockDim.x + threadIdx.x;
    if (i < E) atomicAdd(&deg[dst[i]], 1);
}

// ---- 3-phase exclusive scan over deg[0..n) ----
__global__ __launch_bounds__(256) void scanA_kernel(const int* __restrict__ deg, int n,
                                                    int* __restrict__ bsums) {
    int tid = threadIdx.x;
    int lane = tid & 63;
    int wid = tid >> 6;
    int i = blockIdx.x * 1024 + tid * 4;
    int v0 = (i + 0 < n) ? deg[i + 0] : 0;
    int v1 = (i + 1 < n) ? deg[i + 1] : 0;
    int v2 = (i + 2 < n) ? deg[i + 2] : 0;
    int v3 = (i + 3 < n) ? deg[i + 3] : 0;
    int s = v0 + v1 + v2 + v3;
    #pragma unroll
    for (int off = 32; off > 0; off >>= 1) s += __shfl_down(s, off, 64);
    __shared__ int ws[4];
    if (lane == 0) ws[wid] = s;
    __syncthreads();
    if (tid == 0) bsums[blockIdx.x] = ws[0] + ws[1] + ws[2] + ws[3];
}

__global__ __launch_bounds__(64) void scanB_kernel(int* __restrict__ bsums, int nb,
                                                   int* __restrict__ totp) {
    int lane = threadIdx.x;
    int v = (lane < nb) ? bsums[lane] : 0;
    int x = v;
    #pragma unroll
    for (int off = 1; off < 64; off <<= 1) {
        int y = __shfl_up(x, off, 64);
        if (lane >= off) x += y;
    }
    if (lane < nb) bsums[lane] = x - v;
    if (lane == 63) *totp = x;
}

__global__ __launch_bounds__(256) void scanC_kernel(const int* __restrict__ deg, int n,
                                                    const int* __restrict__ bsums,
                                                    int* __restrict__ offs,
                                                    int* __restrict__ cur,
                                                    float* __restrict__ dinv) {
    int tid = threadIdx.x;
    int lane = tid & 63;
    int wid = tid >> 6;
    int carry = bsums[blockIdx.x];
    int i = blockIdx.x * 1024 + tid * 4;
    int v0 = (i + 0 < n) ? deg[i + 0] : 0;
    int v1 = (i + 1 < n) ? deg[i + 1] : 0;
    int v2 = (i + 2 < n) ? deg[i + 2] : 0;
    int v3 = (i + 3 < n) ? deg[i + 3] : 0;
    int t = v0 + v1 + v2 + v3;
    int x = t;
    #pragma unroll
    for (int off = 1; off < 64; off <<= 1) {
        int y = __shfl_up(x, off, 64);
        if (lane >= off) x += y;
    }
    __shared__ int ws[4];
    if (lane == 63) ws[wid] = x;
    __syncthreads();
    int wprefix = 0;
    #pragma unroll
    for (int w = 0; w < 4; w++) wprefix += (w < wid) ? ws[w] : 0;
    int e0 = carry + wprefix + x - t;
    int e1 = e0 + v0, e2 = e1 + v1, e3 = e2 + v2;
    if (i + 0 < n) { offs[i + 0] = e0; cur[i + 0] = e0; dinv[i + 0] = rsqrtf((float)(v0 + 1)); }
    if (i + 1 < n) { offs[i + 1] = e1; cur[i + 1] = e1; dinv[i + 1] = rsqrtf((float)(v1 + 1)); }
    if (i + 2 < n) { offs[i + 2] = e2; cur[i + 2] = e2; dinv[i + 2] = rsqrtf((float)(v2 + 1)); }
    if (i + 3 < n) { offs[i + 3] = e3; cur[i + 3] = e3; dinv[i + 3] = rsqrtf((float)(v3 + 1)); }
}

// CSR fill: packed {src:16 | bf16(norm):16} per edge (N < 65536)
__global__ __launch_bounds__(256) void fill_kernel(const int* __restrict__ src,
                                                   const int* __restrict__ dst, int E,
                                                   int* __restrict__ cur,
                                                   const float* __restrict__ dinv,
                                                   unsigned int* __restrict__ csr) {
    int i = blockIdx.x * blockDim.x + threadIdx.x;
    if (i < E) {
        int s = src[i];
        int d = dst[i];
        int p = atomicAdd(&cur[d], 1);
        float w = dinv[s] * dinv[d];
        csr[p] = (unsigned int)s | ((unsigned int)f2bf(w) << 16);
    }
}

// W1 [128][128], W2 [128][64] fp32 -> global MFMA-B fragment order, bf16.
// frag elem offset: ((ntg*4+ks)*64 + (n&15) + 16*quad)*8 + j, k=ks*32+quad*8+j
__global__ __launch_bounds__(256) void wt_frag_kernel(const float* __restrict__ W1,
                                                      const float* __restrict__ W2,
                                                      unsigned short* __restrict__ W1f,
                                                      unsigned short* __restrict__ W2f) {
    int idx = blockIdx.x * 256 + threadIdx.x;
    const float* W;
    unsigned short* Wf;
    int n, oct, N;
    if (idx < 2048) { W = W1; Wf = W1f; N = 128; n = idx >> 4; oct = idx & 15; }
    else if (idx < 3072) { W = W2; Wf = W2f; N = 64; int i2 = idx - 2048; n = i2 >> 4; oct = i2 & 15; }
    else return;
    int k0 = oct * 8;
    int ks = k0 >> 5, quad = (k0 >> 3) & 3, ntg = n >> 4;
    short8 v;
    #pragma unroll
    for (int j = 0; j < 8; j++) v[j] = (short)f2bf(W[(k0 + j) * N + n]);
    int off = (((ntg * 4 + ks) * 64) + (n & 15) + 16 * quad) * 8;
    *(short8*)(Wf + off) = v;
}

// ---------------------------------------------------------------------------
// gemm1: h1[M,128] = x[M,128] @ W1 ; A fp32 cast in staging; B-frags direct
// from global (L2-hot). BM=64, 4 waves x (4 m-tiles x 2 n-tiles).
// ---------------------------------------------------------------------------
__global__ __launch_bounds__(256) void gemm1_kernel(const float* __restrict__ A,
                                                    const unsigned short* __restrict__ Bf,
                                                    unsigned short* __restrict__ C,
                                                    int M) {
    constexpr int K = 128, BN = 128;
    __shared__ unsigned short As[64 * K];  // 16 KB

    int tid = threadIdx.x;
    int lane = tid & 63;
    int w = tid >> 6;
    int row0 = blockIdx.x * 64;

    // B fragments straight from global (2 n-tiles per wave)
    short8 bfr[2][4];
    #pragma unroll
    for (int nl = 0; nl < 2; nl++)
        #pragma unroll
        for (int ks = 0; ks < 4; ks++)
            bfr[nl][ks] = *(const short8*)(Bf + ((((w * 2 + nl) * 4 + ks) * 64) + lane) * 8);

    // stage A (fp32 -> bf16, fragment order)
    #pragma unroll
    for (int it = 0; it < 8; it++) {
        int idx = it * 256 + tid;
        int row = idx >> 5, kq = idx & 31;
        int k0 = kq * 4;
        int ks = k0 >> 5, quad = (k0 >> 3) & 3, j0 = k0 & 7, mt = row >> 4;
        ushort4 o = make_ushort4(0, 0, 0, 0);
        int gr = row0 + row;
        if (gr < M) {
            float4 a = *(const float4*)(A + (size_t)gr * K + k0);
            o.x = f2bf(a.x); o.y = f2bf(a.y); o.z = f2bf(a.z); o.w = f2bf(a.w);
        }
        int off = (((mt * 4 + ks) * 64) + (row & 15) + 16 * quad) * 8 + j0;
        *(ushort4*)(As + off) = o;
    }
    __syncthreads();

    f32x4 acc[4][2];
    #pragma unroll
    for (int mt = 0; mt < 4; mt++)
        #pragma unroll
        for (int nl = 0; nl < 2; nl++) acc[mt][nl] = (f32x4){0.f, 0.f, 0.f, 0.f};

    #pragma unroll
    for (int ks = 0; ks < 4; ks++) {
        short8 af[4];
        #pragma unroll
        for (int mt = 0; mt < 4; mt++)
            af[mt] = *(const short8*)(As + (((mt * 4 + ks) * 64) + lane) * 8);
        #pragma unroll
        for (int mt = 0; mt < 4; mt++)
            #pragma unroll
            for (int nl = 0; nl < 2; nl++)
                acc[mt][nl] = __builtin_amdgcn_mfma_f32_16x16x32_bf16(
                    af[mt], bfr[nl][ks], acc[mt][nl], 0, 0, 0);
    }

    int col16 = lane & 15;
    int rowq = lane >> 4;
    #pragma unroll
    for (int mt = 0; mt < 4; mt++) {
        #pragma unroll
        for (int nl = 0; nl < 2; nl++) {
            int gc = (w * 2 + nl) * 16 + col16;
            #pragma unroll
            for (int r = 0; r < 4; r++) {
                int gr = row0 + mt * 16 + rowq * 4 + r;
                if (gr < M) C[(size_t)gr * BN + gc] = f2bf(acc[mt][nl][r]);
            }
        }
    }
}

// ---------------------------------------------------------------------------
// aggmm: fused Agg(layer1) + bias + ReLU + GEMM2.
// Block = 256 thr = 4 waves = 16 nodes (4 per wave, sequential).
// Aggregated rows -> LDS in MFMA A-frag order; wave w computes n-tile w of
// h2 = hmid @ W2 via 4 MFMAs (B-frags preloaded from global).
// ---------------------------------------------------------------------------
__global__ __launch_bounds__(256) void aggmm_kernel(const unsigned short* __restrict__ h1,
                                                    const int* __restrict__ offs,
                                                    const unsigned int* __restrict__ csr,
                                                    const float* __restrict__ dinv,
                                                    const float* __restrict__ b1,
                                                    const unsigned short* __restrict__ W2f,
                                                    unsigned short* __restrict__ h2,
                                                    int n) {
    __shared__ unsigned short As[4 * 64 * 8];  // 4 KB, one 16x128 A-tile

    int tid = threadIdx.x;
    int t = tid & 63;
    int w = tid >> 6;
    int nodebase = blockIdx.x * 16;

    // B fragments for n-tile w (cols w*16..w*16+15 of W2)
    short8 bw[4];
    #pragma unroll
    for (int ks = 0; ks < 4; ks++)
        bw[ks] = *(const short8*)(W2f + (((w * 4 + ks) * 64) + t) * 8);

    float bias0 = b1[t * 2 + 0];
    float bias1 = b1[t * 2 + 1];

    // each wave aggregates 4 nodes (rows w*4 .. w*4+3 of the block tile)
    #pragma unroll
    for (int i = 0; i < 4; i++) {
        int row16 = w * 4 + i;
        int node = nodebase + row16;
        float acc0 = 0.f, acc1 = 0.f;
        if (node < n) {
            float di = dinv[node];
            float sw = di * di;
            unsigned int u = *(const unsigned int*)(h1 + (size_t)node * 128 + t * 2);
            acc0 = bf2f_lo(u) * sw;
            acc1 = bf2f_hi(u) * sw;
            int e0 = offs[node];
            int e1 = offs[node + 1];
            int iters = (e1 - e0 + 3) >> 2;
            for (int it = 0; it < iters; it++) {
                int eb = e0 + it * 4;
                #pragma unroll
                for (int j = 0; j < 4; j++) {
                    int ee = eb + j;
                    int ec = min(ee, e1 - 1);
                    unsigned int pk = csr[ec];
                    float wgt = (ee < e1) ? bf2f_hi(pk) : 0.f;
                    int s = pk & 0xffff;
                    unsigned int hu = *(const unsigned int*)(h1 + (size_t)s * 128 + t * 2);
                    acc0 += bf2f_lo(hu) * wgt;
                    acc1 += bf2f_hi(hu) * wgt;
                }
            }
            acc0 = fmaxf(acc0 + bias0, 0.f);
            acc1 = fmaxf(acc1 + bias1, 0.f);
        }
        // write pair (k=2t, 2t+1) of row row16 into A-frag order
        int k = t * 2;
        int ks = k >> 5, quad = (k >> 3) & 3, j = k & 7;
        unsigned int pack = (unsigned int)f2bf(acc0) | ((unsigned int)f2bf(acc1) << 16);
        *(unsigned int*)(As + ((ks * 64) + row16 + 16 * quad) * 8 + j) = pack;
    }
    __syncthreads();

    // MFMA: 16 rows x n-tile w
    f32x4 acc = (f32x4){0.f, 0.f, 0.f, 0.f};
    #pragma unroll
    for (int ks = 0; ks < 4; ks++) {
        short8 af = *(const short8*)(As + ((ks * 64) + t) * 8);
        acc = __builtin_amdgcn_mfma_f32_16x16x32_bf16(af, bw[ks], acc, 0, 0, 0);
    }

    int col = w * 16 + (t & 15);
    int rowq = t >> 4;
    #pragma unroll
    for (int r = 0; r < 4; r++) {
        int gr = nodebase + rowq * 4 + r;
        if (gr < n) h2[(size_t)gr * 64 + col] = f2bf(acc[r]);
    }
}

// ---------------------------------------------------------------------------
// aggout: Agg(layer2) + bias, fp32 out. One node per wave; 32 lanes per edge
// (2 edges in flight), 4 B loads, halves combined via shfl_xor(32).
// ---------------------------------------------------------------------------
__global__ __launch_bounds__(256) void aggout_kernel(const unsigned short* __restrict__ h2,
                                                     const int* __restrict__ offs,
                                                     const unsigned int* __restrict__ csr,
                                                     const float* __restrict__ dinv,
                                                     const float* __restrict__ b2,
                                                     float* __restrict__ out, int n) {
    int tid = threadIdx.x;
    int t = tid & 63;
    int w = tid >> 6;
    int node = blockIdx.x * 4 + w;
    if (node >= n) return;
    int p = t >> 5;       // which edge of the pair
    int t5 = t & 31;      // feature pair index

    float di = dinv[node];
    float sw = di * di;
    // self loop (half 0 only; half 1 contributes 0)
    unsigned int su = *(const unsigned int*)(h2 + (size_t)node * 64 + t5 * 2);
    float a0 = (p == 0) ? bf2f_lo(su) * sw : 0.f;
    float a1 = (p == 0) ? bf2f_hi(su) * sw : 0.f;

    int e0 = offs[node];
    int e1 = offs[node + 1];
    int iters = (e1 - e0 + 7) >> 3;
    for (int it = 0; it < iters; it++) {
        int eb = e0 + it * 8;
        #pragma unroll
        for (int q = 0; q < 4; q++) {
            int ee = eb + q * 2 + p;
            int ec = min(ee, e1 - 1);
            unsigned int pk = csr[ec];
            float wgt = (ee < e1) ? bf2f_hi(pk) : 0.f;
            int s = pk & 0xffff;
            unsigned int hu = *(const unsigned int*)(h2 + (size_t)s * 64 + t5 * 2);
            a0 += bf2f_lo(hu) * wgt;
            a1 += bf2f_hi(hu) * wgt;
        }
    }
    a0 += __shfl_xor(a0, 32, 64);
    a1 += __shfl_xor(a1, 32, 64);
    if (p == 0) {
        float r0 = a0 + b2[t5 * 2 + 0];
        float r1 = a1 + b2[t5 * 2 + 1];
        *(float2*)(out + (size_t)node * 64 + t5 * 2) = make_float2(r0, r1);
    }
}

extern "C" void kernel_launch(void* const* d_in, const int* in_sizes, int n_in,
                              void* d_out, int out_size, void* d_ws, size_t ws_size,
                              hipStream_t stream) {
    const float* x  = (const float*)d_in[0];
    const int*   ei = (const int*)d_in[1];
    const float* W1 = (const float*)d_in[2];
    const float* b1 = (const float*)d_in[3];
    const float* W2 = (const float*)d_in[4];
    const float* b2 = (const float*)d_in[5];

    const int N = in_sizes[0] / 128;   // 50000
    const int E = in_sizes[1] / 2;     // 500000
    const int* src = ei;
    const int* dst = ei + E;

    char* p = (char*)d_ws;
    auto alloc = [&](size_t bytes) {
        char* r = p;
        p += (bytes + 255) & ~(size_t)255;
        return r;
    };
    int*   degi  = (int*)  alloc((size_t)N * 4);
    float* dinv  = (float*)alloc((size_t)N * 4);
    int*   offs  = (int*)  alloc((size_t)(N + 1) * 4);
    int*   cur   = (int*)  alloc((size_t)N * 4);
    int*   bsums = (int*)  alloc((size_t)64 * 4);
    unsigned int*   csr  = (unsigned int*)alloc((size_t)E * 4);
    unsigned short* W1f  = (unsigned short*)alloc((size_t)128 * 128 * 2);
    unsigned short* W2f  = (unsigned short*)alloc((size_t)64 * 128 * 2);
    unsigned short* h1   = (unsigned short*)alloc((size_t)N * 128 * 2);
    unsigned short* h2   = (unsigned short*)alloc((size_t)N * 64 * 2);
    float* out = (float*)d_out;

    const int NB = (N + 1023) / 1024;

    wt_frag_kernel<<<12, 256, 0, stream>>>(W1, W2, W1f, W2f);
    hipMemsetAsync(degi, 0, (size_t)N * 4, stream);
    count_kernel<<<(E + 255) / 256, 256, 0, stream>>>(dst, E, degi);
    scanA_kernel<<<NB, 256, 0, stream>>>(degi, N, bsums);
    scanB_kernel<<<1, 64, 0, stream>>>(bsums, NB, offs + N);
    scanC_kernel<<<NB, 256, 0, stream>>>(degi, N, bsums, offs, cur, dinv);
    fill_kernel<<<(E + 255) / 256, 256, 0, stream>>>(src, dst, E, cur, dinv, csr);

    gemm1_kernel<<<(N + 63) / 64, 256, 0, stream>>>(x, W1f, h1, N);
    aggmm_kernel<<<(N + 15) / 16, 256, 0, stream>>>(h1, offs, csr, dinv, b1, W2f, h2, N);
    aggout_kernel<<<(N + 3) / 4, 256, 0, stream>>>(h2, offs, csr, dinv, b2, out, N);
}

// Round 6
// 197.189 us; speedup vs baseline: 1.5880x; 1.0027x over previous
//
#include <hip/hip_runtime.h>
#include <hip/hip_bf16.h>
#include <cstddef>

// ---------------------------------------------------------------------------
// 2-layer GCN: h1 = x@W1; hmid = relu(Agg(h1) + b1); h2 = hmid@W2;
// out = Agg(h2) + b2.  Agg = sym-normalized scatter-add with self-loops.
// R1: 3-phase multi-block scan (+fused dinv).
// R2: h1/h2 bf16, agg unroll x4, 4 waves/block.
// R3: MFMA bf16 GEMMs, fragment-order LDS, hmid bf16.
// R4: CSR 4 B/edge (src16|bf16norm), weights in global frag order,
//     gemm2 fused into agg1 (aggmm), branchless padded edge loops.
// R5: gather MLP - aggmm: 32 lanes/edge x 2 edges x unroll4 (8 x 8B loads
//     in flight, shfl_xor combine); aggout: 16 lanes/edge x 4 edges x
//     unroll2, float4 epilogue.
// ---------------------------------------------------------------------------

typedef __attribute__((ext_vector_type(8))) short short8;
typedef __attribute__((ext_vector_type(4))) float f32x4;

__device__ inline unsigned short f2bf(float f) {
    __hip_bfloat16 b = __float2bfloat16(f);
    return *reinterpret_cast<unsigned short*>(&b);
}
__device__ inline float bf2f_lo(unsigned int u) {
    unsigned int v = u << 16;
    return *reinterpret_cast<float*>(&v);
}
__device__ inline float bf2f_hi(unsigned int u) {
    unsigned int v = u & 0xffff0000u;
    return *reinterpret_cast<float*>(&v);
}

__global__ __launch_bounds__(256) void count_kernel(const int* __restrict__ dst, int E,
                                                    int* __restrict__ deg) {
    int i = blockIdx.x * blockDim.x + threadIdx.x;
    if (i < E) atomicAdd(&deg[dst[i]], 1);
}

// ---- 3-phase exclusive scan over deg[0..n) ----
__global__ __launch_bounds__(256) void scanA_kernel(const int* __restrict__ deg, int n,
                                                    int* __restrict__ bsums) {
    int tid = threadIdx.x;
    int lane = tid & 63;
    int wid = tid >> 6;
    int i = blockIdx.x * 1024 + tid * 4;
    int v0 = (i + 0 < n) ? deg[i + 0] : 0;
    int v1 = (i + 1 < n) ? deg[i + 1] : 0;
    int v2 = (i + 2 < n) ? deg[i + 2] : 0;
    int v3 = (i + 3 < n) ? deg[i + 3] : 0;
    int s = v0 + v1 + v2 + v3;
    #pragma unroll
    for (int off = 32; off > 0; off >>= 1) s += __shfl_down(s, off, 64);
    __shared__ int ws[4];
    if (lane == 0) ws[wid] = s;
    __syncthreads();
    if (tid == 0) bsums[blockIdx.x] = ws[0] + ws[1] + ws[2] + ws[3];
}

__global__ __launch_bounds__(64) void scanB_kernel(int* __restrict__ bsums, int nb,
                                                   int* __restrict__ totp) {
    int lane = threadIdx.x;
    int v = (lane < nb) ? bsums[lane] : 0;
    int x = v;
    #pragma unroll
    for (int off = 1; off < 64; off <<= 1) {
        int y = __shfl_up(x, off, 64);
        if (lane >= off) x += y;
    }
    if (lane < nb) bsums[lane] = x - v;
    if (lane == 63) *totp = x;
}

__global__ __launch_bounds__(256) void scanC_kernel(const int* __restrict__ deg, int n,
                                                    const int* __restrict__ bsums,
                                                    int* __restrict__ offs,
                                                    int* __restrict__ cur,
                                                    float* __restrict__ dinv) {
    int tid = threadIdx.x;
    int lane = tid & 63;
    int wid = tid >> 6;
    int carry = bsums[blockIdx.x];
    int i = blockIdx.x * 1024 + tid * 4;
    int v0 = (i + 0 < n) ? deg[i + 0] : 0;
    int v1 = (i + 1 < n) ? deg[i + 1] : 0;
    int v2 = (i + 2 < n) ? deg[i + 2] : 0;
    int v3 = (i + 3 < n) ? deg[i + 3] : 0;
    int t = v0 + v1 + v2 + v3;
    int x = t;
    #pragma unroll
    for (int off = 1; off < 64; off <<= 1) {
        int y = __shfl_up(x, off, 64);
        if (lane >= off) x += y;
    }
    __shared__ int ws[4];
    if (lane == 63) ws[wid] = x;
    __syncthreads();
    int wprefix = 0;
    #pragma unroll
    for (int w = 0; w < 4; w++) wprefix += (w < wid) ? ws[w] : 0;
    int e0 = carry + wprefix + x - t;
    int e1 = e0 + v0, e2 = e1 + v1, e3 = e2 + v2;
    if (i + 0 < n) { offs[i + 0] = e0; cur[i + 0] = e0; dinv[i + 0] = rsqrtf((float)(v0 + 1)); }
    if (i + 1 < n) { offs[i + 1] = e1; cur[i + 1] = e1; dinv[i + 1] = rsqrtf((float)(v1 + 1)); }
    if (i + 2 < n) { offs[i + 2] = e2; cur[i + 2] = e2; dinv[i + 2] = rsqrtf((float)(v2 + 1)); }
    if (i + 3 < n) { offs[i + 3] = e3; cur[i + 3] = e3; dinv[i + 3] = rsqrtf((float)(v3 + 1)); }
}

// CSR fill: packed {src:16 | bf16(norm):16} per edge (N < 65536)
__global__ __launch_bounds__(256) void fill_kernel(const int* __restrict__ src,
                                                   const int* __restrict__ dst, int E,
                                                   int* __restrict__ cur,
                                                   const float* __restrict__ dinv,
                                                   unsigned int* __restrict__ csr) {
    int i = blockIdx.x * blockDim.x + threadIdx.x;
    if (i < E) {
        int s = src[i];
        int d = dst[i];
        int p = atomicAdd(&cur[d], 1);
        float w = dinv[s] * dinv[d];
        csr[p] = (unsigned int)s | ((unsigned int)f2bf(w) << 16);
    }
}

// W1 [128][128], W2 [128][64] fp32 -> global MFMA-B fragment order, bf16.
__global__ __launch_bounds__(256) void wt_frag_kernel(const float* __restrict__ W1,
                                                      const float* __restrict__ W2,
                                                      unsigned short* __restrict__ W1f,
                                                      unsigned short* __restrict__ W2f) {
    int idx = blockIdx.x * 256 + threadIdx.x;
    const float* W;
    unsigned short* Wf;
    int n, oct, N;
    if (idx < 2048) { W = W1; Wf = W1f; N = 128; n = idx >> 4; oct = idx & 15; }
    else if (idx < 3072) { W = W2; Wf = W2f; N = 64; int i2 = idx - 2048; n = i2 >> 4; oct = i2 & 15; }
    else return;
    int k0 = oct * 8;
    int ks = k0 >> 5, quad = (k0 >> 3) & 3, ntg = n >> 4;
    short8 v;
    #pragma unroll
    for (int j = 0; j < 8; j++) v[j] = (short)f2bf(W[(k0 + j) * N + n]);
    int off = (((ntg * 4 + ks) * 64) + (n & 15) + 16 * quad) * 8;
    *(short8*)(Wf + off) = v;
}

// ---------------------------------------------------------------------------
// gemm1: h1[M,128] = x[M,128] @ W1 ; A fp32 cast in staging; B-frags direct
// from global (L2-hot). BM=64, 4 waves x (4 m-tiles x 2 n-tiles).
// ---------------------------------------------------------------------------
__global__ __launch_bounds__(256) void gemm1_kernel(const float* __restrict__ A,
                                                    const unsigned short* __restrict__ Bf,
                                                    unsigned short* __restrict__ C,
                                                    int M) {
    constexpr int K = 128, BN = 128;
    __shared__ unsigned short As[64 * K];  // 16 KB

    int tid = threadIdx.x;
    int lane = tid & 63;
    int w = tid >> 6;
    int row0 = blockIdx.x * 64;

    short8 bfr[2][4];
    #pragma unroll
    for (int nl = 0; nl < 2; nl++)
        #pragma unroll
        for (int ks = 0; ks < 4; ks++)
            bfr[nl][ks] = *(const short8*)(Bf + ((((w * 2 + nl) * 4 + ks) * 64) + lane) * 8);

    #pragma unroll
    for (int it = 0; it < 8; it++) {
        int idx = it * 256 + tid;
        int row = idx >> 5, kq = idx & 31;
        int k0 = kq * 4;
        int ks = k0 >> 5, quad = (k0 >> 3) & 3, j0 = k0 & 7, mt = row >> 4;
        ushort4 o = make_ushort4(0, 0, 0, 0);
        int gr = row0 + row;
        if (gr < M) {
            float4 a = *(const float4*)(A + (size_t)gr * K + k0);
            o.x = f2bf(a.x); o.y = f2bf(a.y); o.z = f2bf(a.z); o.w = f2bf(a.w);
        }
        int off = (((mt * 4 + ks) * 64) + (row & 15) + 16 * quad) * 8 + j0;
        *(ushort4*)(As + off) = o;
    }
    __syncthreads();

    f32x4 acc[4][2];
    #pragma unroll
    for (int mt = 0; mt < 4; mt++)
        #pragma unroll
        for (int nl = 0; nl < 2; nl++) acc[mt][nl] = (f32x4){0.f, 0.f, 0.f, 0.f};

    #pragma unroll
    for (int ks = 0; ks < 4; ks++) {
        short8 af[4];
        #pragma unroll
        for (int mt = 0; mt < 4; mt++)
            af[mt] = *(const short8*)(As + (((mt * 4 + ks) * 64) + lane) * 8);
        #pragma unroll
        for (int mt = 0; mt < 4; mt++)
            #pragma unroll
            for (int nl = 0; nl < 2; nl++)
                acc[mt][nl] = __builtin_amdgcn_mfma_f32_16x16x32_bf16(
                    af[mt], bfr[nl][ks], acc[mt][nl], 0, 0, 0);
    }

    int col16 = lane & 15;
    int rowq = lane >> 4;
    #pragma unroll
    for (int mt = 0; mt < 4; mt++) {
        #pragma unroll
        for (int nl = 0; nl < 2; nl++) {
            int gc = (w * 2 + nl) * 16 + col16;
            #pragma unroll
            for (int r = 0; r < 4; r++) {
                int gr = row0 + mt * 16 + rowq * 4 + r;
                if (gr < M) C[(size_t)gr * BN + gc] = f2bf(acc[mt][nl][r]);
            }
        }
    }
}

// ---------------------------------------------------------------------------
// aggmm: fused Agg(layer1) + bias + ReLU + GEMM2.
// Block = 256 thr = 4 waves = 16 nodes (4 per wave, sequential).
// Edge loop: 32 lanes/edge (uint2 = 4 bf16), 2 edges concurrent, unroll 4
// -> 8 outstanding 8B gathers/wave-iter; halves combined via shfl_xor(32).
// Aggregated rows -> LDS A-frag order; wave w computes n-tile w of
// h2 = hmid @ W2 via 4 MFMAs (B-frags preloaded from global).
// ---------------------------------------------------------------------------
__global__ __launch_bounds__(256) void aggmm_kernel(const unsigned short* __restrict__ h1,
                                                    const int* __restrict__ offs,
                                                    const unsigned int* __restrict__ csr,
                                                    const float* __restrict__ dinv,
                                                    const float* __restrict__ b1,
                                                    const unsigned short* __restrict__ W2f,
                                                    unsigned short* __restrict__ h2,
                                                    int n) {
    __shared__ unsigned short As[4 * 64 * 8];  // 4 KB, one 16x128 A-tile

    int tid = threadIdx.x;
    int t = tid & 63;
    int w = tid >> 6;
    int p = t >> 5;      // edge slot (0/1)
    int t5 = t & 31;     // feature quad index (4 bf16)
    int nodebase = blockIdx.x * 16;

    // B fragments for n-tile w (cols w*16..w*16+15 of W2)
    short8 bw[4];
    #pragma unroll
    for (int ks = 0; ks < 4; ks++)
        bw[ks] = *(const short8*)(W2f + (((w * 4 + ks) * 64) + t) * 8);

    float4 bias = *(const float4*)(b1 + t5 * 4);

    #pragma unroll
    for (int i = 0; i < 4; i++) {
        int row16 = w * 4 + i;
        int node = nodebase + row16;
        float a0 = 0.f, a1 = 0.f, a2 = 0.f, a3 = 0.f;
        if (node < n) {
            float di = dinv[node];
            float sw = di * di;
            if (p == 0) {
                uint2 su = *(const uint2*)(h1 + (size_t)node * 128 + t5 * 4);
                a0 = bf2f_lo(su.x) * sw; a1 = bf2f_hi(su.x) * sw;
                a2 = bf2f_lo(su.y) * sw; a3 = bf2f_hi(su.y) * sw;
            }
            int e0 = offs[node];
            int e1 = offs[node + 1];
            int iters = (e1 - e0 + 7) >> 3;
            for (int it = 0; it < iters; it++) {
                int eb = e0 + it * 8;
                #pragma unroll
                for (int j = 0; j < 4; j++) {
                    int ee = eb + j * 2 + p;
                    int ec = min(ee, e1 - 1);
                    unsigned int pk = csr[ec];
                    float wgt = (ee < e1) ? bf2f_hi(pk) : 0.f;
                    int s = pk & 0xffff;
                    uint2 hu = *(const uint2*)(h1 + (size_t)s * 128 + t5 * 4);
                    a0 += bf2f_lo(hu.x) * wgt; a1 += bf2f_hi(hu.x) * wgt;
                    a2 += bf2f_lo(hu.y) * wgt; a3 += bf2f_hi(hu.y) * wgt;
                }
            }
        }
        a0 += __shfl_xor(a0, 32, 64);
        a1 += __shfl_xor(a1, 32, 64);
        a2 += __shfl_xor(a2, 32, 64);
        a3 += __shfl_xor(a3, 32, 64);
        if (p == 0) {
            if (node < n) {
                a0 = fmaxf(a0 + bias.x, 0.f);
                a1 = fmaxf(a1 + bias.y, 0.f);
                a2 = fmaxf(a2 + bias.z, 0.f);
                a3 = fmaxf(a3 + bias.w, 0.f);
            }
            int k0 = t5 * 4;
            int ks = k0 >> 5, quad = (k0 >> 3) & 3, j0 = k0 & 7;
            ushort4 pk4 = make_ushort4(f2bf(a0), f2bf(a1), f2bf(a2), f2bf(a3));
            *(ushort4*)(As + ((ks * 64) + row16 + 16 * quad) * 8 + j0) = pk4;
        }
    }
    __syncthreads();

    // MFMA: 16 rows x n-tile w
    f32x4 acc = (f32x4){0.f, 0.f, 0.f, 0.f};
    #pragma unroll
    for (int ks = 0; ks < 4; ks++) {
        short8 af = *(const short8*)(As + ((ks * 64) + t) * 8);
        acc = __builtin_amdgcn_mfma_f32_16x16x32_bf16(af, bw[ks], acc, 0, 0, 0);
    }

    int col = w * 16 + (t & 15);
    int rowq = t >> 4;
    #pragma unroll
    for (int r = 0; r < 4; r++) {
        int gr = nodebase + rowq * 4 + r;
        if (gr < n) h2[(size_t)gr * 64 + col] = f2bf(acc[r]);
    }
}

// ---------------------------------------------------------------------------
// aggout: Agg(layer2) + bias, fp32 out. One node per wave; 16 lanes/edge
// (uint2 = 4 bf16), 4 edges concurrent, unroll 2 -> 8 outstanding gathers;
// combine via shfl_xor(16)+shfl_xor(32); float4 epilogue.
// ---------------------------------------------------------------------------
__global__ __launch_bounds__(256) void aggout_kernel(const unsigned short* __restrict__ h2,
                                                     const int* __restrict__ offs,
                                                     const unsigned int* __restrict__ csr,
                                                     const float* __restrict__ dinv,
                                                     const float* __restrict__ b2,
                                                     float* __restrict__ out, int n) {
    int tid = threadIdx.x;
    int t = tid & 63;
    int w = tid >> 6;
    int node = blockIdx.x * 4 + w;
    if (node >= n) return;
    int p = t >> 4;      // edge slot (0..3)
    int t4 = t & 15;     // feature quad index

    float a0 = 0.f, a1 = 0.f, a2 = 0.f, a3 = 0.f;
    float di = dinv[node];
    float sw = di * di;
    if (p == 0) {
        uint2 su = *(const uint2*)(h2 + (size_t)node * 64 + t4 * 4);
        a0 = bf2f_lo(su.x) * sw; a1 = bf2f_hi(su.x) * sw;
        a2 = bf2f_lo(su.y) * sw; a3 = bf2f_hi(su.y) * sw;
    }

    int e0 = offs[node];
    int e1 = offs[node + 1];
    int iters = (e1 - e0 + 7) >> 3;
    for (int it = 0; it < iters; it++) {
        int eb = e0 + it * 8;
        #pragma unroll
        for (int j = 0; j < 2; j++) {
            int ee = eb + j * 4 + p;
            int ec = min(ee, e1 - 1);
            unsigned int pk = csr[ec];
            float wgt = (ee < e1) ? bf2f_hi(pk) : 0.f;
            int s = pk & 0xffff;
            uint2 hu = *(const uint2*)(h2 + (size_t)s * 64 + t4 * 4);
            a0 += bf2f_lo(hu.x) * wgt; a1 += bf2f_hi(hu.x) * wgt;
            a2 += bf2f_lo(hu.y) * wgt; a3 += bf2f_hi(hu.y) * wgt;
        }
    }
    a0 += __shfl_xor(a0, 16, 64); a1 += __shfl_xor(a1, 16, 64);
    a2 += __shfl_xor(a2, 16, 64); a3 += __shfl_xor(a3, 16, 64);
    a0 += __shfl_xor(a0, 32, 64); a1 += __shfl_xor(a1, 32, 64);
    a2 += __shfl_xor(a2, 32, 64); a3 += __shfl_xor(a3, 32, 64);
    if (p == 0) {
        float4 bb = *(const float4*)(b2 + t4 * 4);
        *(float4*)(out + (size_t)node * 64 + t4 * 4) =
            make_float4(a0 + bb.x, a1 + bb.y, a2 + bb.z, a3 + bb.w);
    }
}

extern "C" void kernel_launch(void* const* d_in, const int* in_sizes, int n_in,
                              void* d_out, int out_size, void* d_ws, size_t ws_size,
                              hipStream_t stream) {
    const float* x  = (const float*)d_in[0];
    const int*   ei = (const int*)d_in[1];
    const float* W1 = (const float*)d_in[2];
    const float* b1 = (const float*)d_in[3];
    const float* W2 = (const float*)d_in[4];
    const float* b2 = (const float*)d_in[5];

    const int N = in_sizes[0] / 128;   // 50000
    const int E = in_sizes[1] / 2;     // 500000
    const int* src = ei;
    const int* dst = ei + E;

    char* p = (char*)d_ws;
    auto alloc = [&](size_t bytes) {
        char* r = p;
        p += (bytes + 255) & ~(size_t)255;
        return r;
    };
    int*   degi  = (int*)  alloc((size_t)N * 4);
    float* dinv  = (float*)alloc((size_t)N * 4);
    int*   offs  = (int*)  alloc((size_t)(N + 1) * 4);
    int*   cur   = (int*)  alloc((size_t)N * 4);
    int*   bsums = (int*)  alloc((size_t)64 * 4);
    unsigned int*   csr  = (unsigned int*)alloc((size_t)E * 4);
    unsigned short* W1f  = (unsigned short*)alloc((size_t)128 * 128 * 2);
    unsigned short* W2f  = (unsigned short*)alloc((size_t)64 * 128 * 2);
    unsigned short* h1   = (unsigned short*)alloc((size_t)N * 128 * 2);
    unsigned short* h2   = (unsigned short*)alloc((size_t)N * 64 * 2);
    float* out = (float*)d_out;

    const int NB = (N + 1023) / 1024;

    wt_frag_kernel<<<12, 256, 0, stream>>>(W1, W2, W1f, W2f);
    hipMemsetAsync(degi, 0, (size_t)N * 4, stream);
    count_kernel<<<(E + 255) / 256, 256, 0, stream>>>(dst, E, degi);
    scanA_kernel<<<NB, 256, 0, stream>>>(degi, N, bsums);
    scanB_kernel<<<1, 64, 0, stream>>>(bsums, NB, offs + N);
    scanC_kernel<<<NB, 256, 0, stream>>>(degi, N, bsums, offs, cur, dinv);
    fill_kernel<<<(E + 255) / 256, 256, 0, stream>>>(src, dst, E, cur, dinv, csr);

    gemm1_kernel<<<(N + 63) / 64, 256, 0, stream>>>(x, W1f, h1, N);
    aggmm_kernel<<<(N + 15) / 16, 256, 0, stream>>>(h1, offs, csr, dinv, b1, W2f, h2, N);
    aggout_kernel<<<(N + 3) / 4, 256, 0, stream>>>(h2, offs, csr, dinv, b2, out, N);
}